// Round 11
// baseline (323.257 us; speedup 1.0000x reference)
//
#include <hip/hip_runtime.h>
#include <hip/hip_bf16.h>

#define NEG_SLOPE 0.1f
#define BN_EPS 1e-5f
#define MDV 25000

typedef __bf16 bf16_t;
typedef bf16_t bf16x8 __attribute__((ext_vector_type(8)));
typedef bf16_t bf16x4 __attribute__((ext_vector_type(4)));
typedef float f32x4 __attribute__((ext_vector_type(4)));

__device__ __forceinline__ float leaky(float x) { return x >= 0.0f ? x : NEG_SLOPE * x; }

// ---------------------------------------------------------------------------
// histogram both index arrays in one pass
__global__ void k_hist_both(const int* __restrict__ inv, int* __restrict__ cntD,
                            const int* __restrict__ nxt, int* __restrict__ cntI,
                            int N, int NF) {
    int f = blockIdx.x * 256 + threadIdx.x;
    if (f < N) atomicAdd(&cntD[inv[f]], 1);
    if (f < NF) atomicAdd(&cntI[nxt[f]], 1);
}

// ---------------------------------------------------------------------------
// grain scan: block0 scans cntD[MD]->rowstartD, block1 scans cntI[MO]->rowstart
__global__ __launch_bounds__(1024) void k_scan_both(
        const int* __restrict__ cntD, int* __restrict__ rowstartD, int MD,
        const int* __restrict__ cntI, int* __restrict__ rowstart, int MO) {
    const int* in; int* o1; int M;
    if (blockIdx.x == 0) { in = cntD; o1 = rowstartD; M = MD; }
    else                 { in = cntI; o1 = rowstart;  M = MO; }
    int t = threadIdx.x;
    int T = (M + 1023) >> 10;
    int base = t * T;
    int s1 = 0;
    for (int i = 0; i < T; i++) {
        int idx = base + i;
        s1 += (idx < M) ? in[idx] : 0;
    }
    __shared__ int sa[1024], sb[1024];
    sa[t] = s1;
    __syncthreads();
    int *p = sa, *q = sb;
    for (int off = 1; off < 1024; off <<= 1) {
        int v1 = p[t] + ((t >= off) ? p[t - off] : 0);
        q[t] = v1;
        __syncthreads();
        int* tmp = p; p = q; q = tmp;
    }
    int run1 = p[t] - s1;   // exclusive prefix of this thread's grain
    for (int i = 0; i < T; i++) {
        int idx = base + i;
        if (idx < M) {
            o1[idx] = run1;
            run1 += in[idx];
        }
    }
    if (t == 1023) o1[M] = run1;
}

// ---------------------------------------------------------------------------
// fill both CSR lists; csrD holds f; csrAB holds (cur[f], inv[cur[f]]) packed
__global__ void k_fill_both(const int* __restrict__ inv, const int* __restrict__ rowstartD,
                            int* __restrict__ cursorD, int* __restrict__ csrD,
                            const int* __restrict__ nxt, const int* __restrict__ cur,
                            const int* __restrict__ rowstart, int* __restrict__ cursor,
                            int2* __restrict__ csrAB, int N, int NF) {
    int f = blockIdx.x * 256 + threadIdx.x;
    if (f < N) {
        int v = inv[f];
        int pos = atomicAdd(&cursorD[v], 1);
        csrD[rowstartD[v] + pos] = f;
    }
    if (f < NF) {
        int v = nxt[f];
        int pos = atomicAdd(&cursor[v], 1);
        int c = cur[f];
        csrAB[rowstart[v] + pos] = make_int2(c, inv[c]);
    }
}

// ---------------------------------------------------------------------------
// voxel mean pooling via CSR gather: one wave per voxel, x2 unrolled loads
__global__ __launch_bounds__(256) void k_downsum(
        const float* __restrict__ feat, const int* __restrict__ csrD,
        const int* __restrict__ rowstartD, const int* __restrict__ cntD,
        float* __restrict__ dsum, int MD) {
    int w = threadIdx.x >> 6, l = threadIdx.x & 63;
    int vox = blockIdx.x * 4 + w;
    if (vox >= MD) return;
    int cnt = cntD[vox];
    int start = rowstartD[vox];
    float s = 0.f;
    int p = 0;
    for (; p + 2 <= cnt; p += 2) {
        int r0 = csrD[start + p];
        int r1 = csrD[start + p + 1];
        s += feat[(size_t)r0 * 64 + l] + feat[(size_t)r1 * 64 + l];
    }
    if (p < cnt) s += feat[(size_t)csrD[start + p] * 64 + l];
    dsum[(size_t)vox * 64 + l] = s / fmaxf((float)cnt, 1.0f);
}

// ---------------------------------------------------------------------------
// MLP64 + BN stats v2: W staged in LDS, wave-private activation row (no
// in-loop barriers), 4-way split accumulator, grid 2048 (8 blocks/CU).
__global__ __launch_bounds__(256) void k_mlp64(
        const float* __restrict__ in, const float* __restrict__ W,
        const float* __restrict__ bias, float* __restrict__ out,
        float* __restrict__ ssum, float* __restrict__ ssq, int M) {
    __shared__ float Wl[64 * 64];
    __shared__ float a[4][64];
    int tid = threadIdx.x;
    int w = tid >> 6, c = tid & 63;
    {
        const float4* src = reinterpret_cast<const float4*>(W);
        float4* dst = reinterpret_cast<float4*>(Wl);
        for (int i = tid; i < 1024; i += 256) dst[i] = src[i];
    }
    float bv = bias[c];
    __syncthreads();
    float ls = 0.0f, lq = 0.0f;
    int ntiles = (M + 3) >> 2;
    for (int tile = blockIdx.x; tile < ntiles; tile += gridDim.x) {
        int row = tile * 4 + w;
        float v = (row < M) ? in[(size_t)row * 64 + c] : 0.0f;
        a[w][c] = v;   // wave-private row: no block barrier needed (cf. k_pool_mlp64 precedent)
        float a0 = bv, a1 = 0.f, a2 = 0.f, a3 = 0.f;
#pragma unroll
        for (int k = 0; k < 64; k += 4) {
            a0 = fmaf(a[w][k + 0], Wl[(k + 0) * 64 + c], a0);
            a1 = fmaf(a[w][k + 1], Wl[(k + 1) * 64 + c], a1);
            a2 = fmaf(a[w][k + 2], Wl[(k + 2) * 64 + c], a2);
            a3 = fmaf(a[w][k + 3], Wl[(k + 3) * 64 + c], a3);
        }
        float acc = leaky((a0 + a1) + (a2 + a3));
        if (row < M) {
            out[(size_t)row * 64 + c] = acc;
            ls += acc;
            lq += acc * acc;
        }
    }
    __syncthreads();
    a[w][c] = ls;
    __syncthreads();
    if (w == 0) atomicAdd(&ssum[c], a[0][c] + a[1][c] + a[2][c] + a[3][c]);
    __syncthreads();
    a[w][c] = lq;
    __syncthreads();
    if (w == 0) atomicAdd(&ssq[c], a[0][c] + a[1][c] + a[2][c] + a[3][c]);
}

// ---------------------------------------------------------------------------
// fold BatchNorm into the next layer's weights (f32 output)
__global__ void k_fold(const float* __restrict__ ssum, const float* __restrict__ ssq,
                       const float* __restrict__ g, const float* __restrict__ be,
                       const float* __restrict__ W, const float* __restrict__ b,
                       float* __restrict__ Wp, float* __restrict__ bp, int M, int Cn) {
    int j = threadIdx.x;
    if (j >= Cn) return;
    float fM = (float)M;
    float accb = b[j];
    for (int k = 0; k < 64; k++) {
        float mu = ssum[k] / fM;
        float var = ssq[k] / fM - mu * mu;
        float rstd = rsqrtf(var + BN_EPS);
        float ak = g[k] * rstd;
        float ck = be[k] - mu * ak;
        float w = W[k * Cn + j];
        Wp[k * Cn + j] = ak * w;
        accb = fmaf(ck, w, accb);
    }
    bp[j] = accb;
}

// ---------------------------------------------------------------------------
// fold BN2 into W3 [64x128], writing bf16 MFMA-B packed fragments directly
__global__ void k_fold_packed(const float* __restrict__ ssum, const float* __restrict__ ssq,
                              const float* __restrict__ g, const float* __restrict__ be,
                              const float* __restrict__ W, const float* __restrict__ b,
                              bf16_t* __restrict__ P, float* __restrict__ bp, int M) {
    int j = threadIdx.x;   // 0..127 output column
    if (j >= 128) return;
    float fM = (float)M;
    float accb = b[j];
    int n = j >> 4, jr = j & 15;
    for (int k = 0; k < 64; k++) {
        float mu = ssum[k] / fM;
        float var = ssq[k] / fM - mu * mu;
        float rstd = rsqrtf(var + BN_EPS);
        float ak = g[k] * rstd;
        float ck = be[k] - mu * ak;
        float w = W[k * 128 + j];
        accb = fmaf(ck, w, accb);
        int s = k >> 5, l = ((k >> 3) & 3) * 16 + jr, jj = k & 7;
        P[((size_t)((s * 8 + n) * 64 + l)) * 8 + jj] = (bf16_t)(ak * w);
    }
    bp[j] = accb;
}

// ---------------------------------------------------------------------------
// Pack W4/W5/W_in into bf16 MFMA-B fragment order
__global__ void k_pack(const float* __restrict__ W4, const float* __restrict__ W5,
                       const float* __restrict__ Win,
                       bf16_t* __restrict__ P1, bf16_t* __restrict__ P2, bf16_t* __restrict__ P0) {
    int tid = blockIdx.x * 256 + threadIdx.x;
    const float* W; bf16_t* P; int t;
    if (tid < 4096)      { W = W4;  P = P1; t = tid; }
    else if (tid < 6144) { W = W5;  P = P2; t = tid - 4096; }
    else if (tid < 7168) { W = Win; P = P0; t = tid - 6144; }
    else return;
    int l = t & 63;
    int sn = t >> 6;
    int col = (sn & 7) * 16 + (l & 15);
    int k0 = (sn >> 3) * 32 + (l >> 4) * 8;
    bf16_t* dst = P + (size_t)t * 8;
#pragma unroll
    for (int j = 0; j < 8; j++) dst[j] = (bf16_t)W[(size_t)(k0 + j) * 128 + col];
}

// ---------------------------------------------------------------------------
// k_two_gemm: out[M,128] = leaky(in[M,64] @ Pa + ba) @ Pb (+ bb)   (bf16 out)
__global__ __launch_bounds__(256) void k_two_gemm(
        const float* __restrict__ in, const bf16_t* __restrict__ Pa,
        const float* __restrict__ ba, const bf16_t* __restrict__ Pb,
        const float* __restrict__ bb, bf16_t* __restrict__ out, int M) {
    __shared__ bf16_t A[64 * 64];     // 8 KB
    __shared__ bf16_t C[64 * 128];    // 16 KB
    int tid = threadIdx.x;
    int base = blockIdx.x * 64;
    int valid = M - base; if (valid > 64) valid = 64;

    {   // stage A: thread covers row=tid>>2, 16 cols, f32->bf16, swizzled
        int r = tid >> 2, q = tid & 3;
        float4 v[4];
        if (r < valid) {
            const float4* src = reinterpret_cast<const float4*>(in + (size_t)(base + r) * 64 + q * 16);
#pragma unroll
            for (int i = 0; i < 4; i++) v[i] = src[i];
        } else {
#pragma unroll
            for (int i = 0; i < 4; i++) v[i] = make_float4(0.f, 0.f, 0.f, 0.f);
        }
        bf16x8 h0, h1;
#pragma unroll
        for (int i = 0; i < 2; i++) {
            h0[i * 4 + 0] = (bf16_t)v[i].x; h0[i * 4 + 1] = (bf16_t)v[i].y;
            h0[i * 4 + 2] = (bf16_t)v[i].z; h0[i * 4 + 3] = (bf16_t)v[i].w;
            h1[i * 4 + 0] = (bf16_t)v[2 + i].x; h1[i * 4 + 1] = (bf16_t)v[2 + i].y;
            h1[i * 4 + 2] = (bf16_t)v[2 + i].z; h1[i * 4 + 3] = (bf16_t)v[2 + i].w;
        }
        int xa = (r & 7) << 3;
        *reinterpret_cast<bf16x8*>(&A[r * 64 + ((q * 16) ^ xa)]) = h0;
        *reinterpret_cast<bf16x8*>(&A[r * 64 + ((q * 16 + 8) ^ xa)]) = h1;
    }
    __syncthreads();

    int w = tid >> 6, l = tid & 63;
    int lg = l >> 4, lr = l & 15;
    int xr = (lr & 7) << 3;

    // GEMM a: K=64 (2 k-steps), acc init ba, leaky -> C
    f32x4 acc[4][2];
#pragma unroll
    for (int t = 0; t < 2; t++) {
        float bv = ba[w * 32 + t * 16 + lr];
#pragma unroll
        for (int m = 0; m < 4; m++) acc[m][t] = (f32x4){bv, bv, bv, bv};
    }
#pragma unroll
    for (int s = 0; s < 2; s++) {
        bf16x8 a[4];
#pragma unroll
        for (int m = 0; m < 4; m++)
            a[m] = *reinterpret_cast<const bf16x8*>(&A[(m * 16 + lr) * 64 + (((s * 4 + lg) * 8) ^ xr)]);
#pragma unroll
        for (int t = 0; t < 2; t++) {
            bf16x8 b = *reinterpret_cast<const bf16x8*>(Pa + ((size_t)(s * 8 + w * 2 + t) * 64 + l) * 8);
#pragma unroll
            for (int m = 0; m < 4; m++)
                acc[m][t] = __builtin_amdgcn_mfma_f32_16x16x32_bf16(a[m], b, acc[m][t], 0, 0, 0);
        }
    }
#pragma unroll
    for (int m = 0; m < 4; m++)
#pragma unroll
        for (int t = 0; t < 2; t++)
#pragma unroll
            for (int rr = 0; rr < 4; rr++) {
                int row = m * 16 + lg * 4 + rr;
                int col = w * 32 + t * 16 + lr;
                C[row * 128 + (col ^ ((row & 7) << 3))] = (bf16_t)leaky(acc[m][t][rr]);
            }
    __syncthreads();

    // GEMM b: K=128 (4 k-steps), acc init bb (or 0)
    f32x4 acc2[4][2];
#pragma unroll
    for (int t = 0; t < 2; t++) {
        float bv = bb ? bb[w * 32 + t * 16 + lr] : 0.0f;
#pragma unroll
        for (int m = 0; m < 4; m++) acc2[m][t] = (f32x4){bv, bv, bv, bv};
    }
#pragma unroll
    for (int s = 0; s < 4; s++) {
        bf16x8 a[4];
#pragma unroll
        for (int m = 0; m < 4; m++)
            a[m] = *reinterpret_cast<const bf16x8*>(&C[(m * 16 + lr) * 128 + ((s * 32 + lg * 8) ^ xr)]);
#pragma unroll
        for (int t = 0; t < 2; t++) {
            bf16x8 b = *reinterpret_cast<const bf16x8*>(Pb + ((size_t)(s * 8 + w * 2 + t) * 64 + l) * 8);
#pragma unroll
            for (int m = 0; m < 4; m++)
                acc2[m][t] = __builtin_amdgcn_mfma_f32_16x16x32_bf16(a[m], b, acc2[m][t], 0, 0, 0);
        }
    }
    __syncthreads();   // all C reads complete before overwrite

    // overwrite C with acc2 (no activation), then coalesced 16B write-out
#pragma unroll
    for (int m = 0; m < 4; m++)
#pragma unroll
        for (int t = 0; t < 2; t++)
#pragma unroll
            for (int rr = 0; rr < 4; rr++) {
                int row = m * 16 + lg * 4 + rr;
                int col = w * 32 + t * 16 + lr;
                C[row * 128 + (col ^ ((row & 7) << 3))] = (bf16_t)acc2[m][t][rr];
            }
    __syncthreads();
#pragma unroll
    for (int i = 0; i < 4; i++) {
        int u = tid + i * 256;
        int row = u >> 4, seg = u & 15;
        if (row < valid) {
            bf16x8 val = *reinterpret_cast<const bf16x8*>(&C[row * 128 + ((seg * 8) ^ ((row & 7) << 3))]);
            *reinterpret_cast<bf16x8*>(&out[(size_t)(base + row) * 128 + seg * 8]) = val;
        }
    }
}

// ---------------------------------------------------------------------------
// k_gather_mean v2: one wave per output voxel; 2 points per instruction
// (lanes 0-31 cover point p, lanes 32-63 point p+1; bf16x4 per lane), x2 unroll.
__global__ __launch_bounds__(256) void k_gather_mean(
        const bf16_t* __restrict__ z1, const bf16_t* __restrict__ z2,
        const int2* __restrict__ csrAB, const int* __restrict__ rowstart,
        const int* __restrict__ cntI, bf16_t* __restrict__ meanB, int MO) {
    int w = threadIdx.x >> 6, l = threadIdx.x & 63;
    int half = l >> 5, sub = l & 31;
    int v = blockIdx.x * 4 + w;
    if (v >= MO) return;
    int cnt = cntI[v];
    int start = rowstart[v];
    float s[4] = {0.f, 0.f, 0.f, 0.f};
    int p = 0;
    for (; p + 4 <= cnt; p += 4) {
        int2 ea = csrAB[start + p + half];
        int2 eb = csrAB[start + p + 2 + half];
        bf16x4 za0 = *reinterpret_cast<const bf16x4*>(&z1[(size_t)ea.x * 128 + sub * 4]);
        bf16x4 zb0 = *reinterpret_cast<const bf16x4*>(&z2[(size_t)ea.y * 128 + sub * 4]);
        bf16x4 za1 = *reinterpret_cast<const bf16x4*>(&z1[(size_t)eb.x * 128 + sub * 4]);
        bf16x4 zb1 = *reinterpret_cast<const bf16x4*>(&z2[(size_t)eb.y * 128 + sub * 4]);
#pragma unroll
        for (int j = 0; j < 4; j++) {
            s[j] += leaky((float)za0[j] + (float)zb0[j]);
            s[j] += leaky((float)za1[j] + (float)zb1[j]);
        }
    }
    for (; p + 2 <= cnt; p += 2) {
        int2 e = csrAB[start + p + half];
        bf16x4 za = *reinterpret_cast<const bf16x4*>(&z1[(size_t)e.x * 128 + sub * 4]);
        bf16x4 zb = *reinterpret_cast<const bf16x4*>(&z2[(size_t)e.y * 128 + sub * 4]);
#pragma unroll
        for (int j = 0; j < 4; j++) s[j] += leaky((float)za[j] + (float)zb[j]);
    }
    if (p < cnt && half == 0) {
        int2 e = csrAB[start + p];
        bf16x4 za = *reinterpret_cast<const bf16x4*>(&z1[(size_t)e.x * 128 + sub * 4]);
        bf16x4 zb = *reinterpret_cast<const bf16x4*>(&z2[(size_t)e.y * 128 + sub * 4]);
#pragma unroll
        for (int j = 0; j < 4; j++) s[j] += leaky((float)za[j] + (float)zb[j]);
    }
    float sc = (cnt > 0) ? (1.0f / (float)cnt) : 0.0f;
    bf16x4 mv;
#pragma unroll
    for (int j = 0; j < 4; j++) {
        s[j] += __shfl_xor(s[j], 32);
        mv[j] = (bf16_t)(s[j] * sc);
    }
    if (half == 0)
        *reinterpret_cast<bf16x4*>(&meanB[(size_t)v * 128 + sub * 4]) = mv;
}

// ---------------------------------------------------------------------------
// k_vox2: out[MO,128] f32 = meanB[MO,128] @ P2 + b5, masked to 0 where cnt==0
__global__ __launch_bounds__(256) void k_vox2(
        const bf16_t* __restrict__ meanB, const int* __restrict__ cntI,
        const bf16_t* __restrict__ P2, const float* __restrict__ b5,
        float* __restrict__ outp, int MO) {
    int tid = threadIdx.x;
    int base = blockIdx.x * 64;
    int w = tid >> 6, l = tid & 63;
    int lg = l >> 4, lr = l & 15;
    f32x4 acc[4][2];
#pragma unroll
    for (int t = 0; t < 2; t++) {
        float bv = b5[w * 32 + t * 16 + lr];
#pragma unroll
        for (int m = 0; m < 4; m++) acc[m][t] = (f32x4){bv, bv, bv, bv};
    }
#pragma unroll
    for (int s = 0; s < 4; s++) {
        bf16x8 a[4];
#pragma unroll
        for (int m = 0; m < 4; m++) {
            int row = base + m * 16 + lr;
            a[m] = *reinterpret_cast<const bf16x8*>(&meanB[(size_t)row * 128 + (s * 4 + lg) * 8]);
        }
#pragma unroll
        for (int t = 0; t < 2; t++) {
            bf16x8 b = *reinterpret_cast<const bf16x8*>(P2 + ((size_t)(s * 8 + w * 2 + t) * 64 + l) * 8);
#pragma unroll
            for (int m = 0; m < 4; m++)
                acc[m][t] = __builtin_amdgcn_mfma_f32_16x16x32_bf16(a[m], b, acc[m][t], 0, 0, 0);
        }
    }
#pragma unroll
    for (int m = 0; m < 4; m++)
#pragma unroll
        for (int t = 0; t < 2; t++)
#pragma unroll
            for (int rr = 0; rr < 4; rr++) {
                int row = base + m * 16 + lg * 4 + rr;
                if (row < MO) {
                    float val = (cntI[row] > 0) ? acc[m][t][rr] : 0.0f;
                    outp[(size_t)row * 128 + w * 32 + t * 16 + lr] = val;
                }
            }
}

// ---------------------------------------------------------------------------
extern "C" void kernel_launch(void* const* d_in, const int* in_sizes, int n_in,
                              void* d_out, int out_size, void* d_ws, size_t ws_size,
                              hipStream_t stream) {
    const float* feat = (const float*)d_in[0];
    const int*   inv  = (const int*)d_in[1];
    const int*   cur  = (const int*)d_in[2];
    const int*   nxt  = (const int*)d_in[3];
    const float* W_in = (const float*)d_in[6];
    const float* b_in = (const float*)d_in[7];
    const float* W1   = (const float*)d_in[8];
    const float* b1   = (const float*)d_in[9];
    const float* g1   = (const float*)d_in[10];
    const float* be1  = (const float*)d_in[11];
    const float* W2   = (const float*)d_in[12];
    const float* b2   = (const float*)d_in[13];
    const float* g2   = (const float*)d_in[14];
    const float* be2  = (const float*)d_in[15];
    const float* W3   = (const float*)d_in[16];
    const float* b3   = (const float*)d_in[17];
    const float* W4   = (const float*)d_in[18];
    const float* b4   = (const float*)d_in[19];
    const float* W5   = (const float*)d_in[20];
    const float* b5   = (const float*)d_in[21];

    const int N  = in_sizes[0] / 64;
    const int NF = in_sizes[2];
    const int MO = out_size / 128;
    const int MD = MDV;   // n_down (device scalar; fixed problem size)

    float* ws = (float*)d_ws;
    size_t off = 0;
    // ---- zeroed region (stats + counters only) ----
    float* ssum1 = ws + off; off += 64;
    float* ssq1  = ws + off; off += 64;
    float* ssum2 = ws + off; off += 64;
    float* ssq2  = ws + off; off += 64;
    int* cntD    = (int*)(ws + off); off += (size_t)MD;
    int* cursorD = (int*)(ws + off); off += (size_t)MD;
    int* cntI    = (int*)(ws + off); off += (size_t)MO;
    int* cursor  = (int*)(ws + off); off += (size_t)MO;
    size_t zeroElems = off;
    // ---- non-zeroed ----
    float* dsum = ws + off; off += (size_t)MD * 64;
    float* t1   = ws + off; off += (size_t)MD * 64;
    float* t2   = ws + off; off += (size_t)MD * 64;
    float* Wp2  = ws + off; off += 64 * 64;
    float* bp2  = ws + off; off += 64;
    float* bp3  = ws + off; off += 128;
    int* rowstartD = (int*)(ws + off); off += (size_t)MD + 1;
    int* rowstart  = (int*)(ws + off); off += (size_t)MO + 1;
    int* csrD      = (int*)(ws + off); off += (size_t)N;
    off = (off + 1) & ~(size_t)1;   // 8B align for int2
    int2* csrAB    = (int2*)(ws + off); off += (size_t)NF * 2;
    bf16_t* bws = (bf16_t*)(ws + off);
    size_t boff = 0;
    bf16_t* z1    = bws + boff; boff += (size_t)N * 128;
    bf16_t* z2    = bws + boff; boff += (size_t)MD * 128;
    bf16_t* meanB = bws + boff; boff += (size_t)MO * 128 + 4096;  // +slack for tail OOB reads
    bf16_t* P0    = bws + boff; boff += 8192;
    bf16_t* P1    = bws + boff; boff += 32768;
    bf16_t* P2    = bws + boff; boff += 16384;
    bf16_t* P3    = bws + boff; boff += 8192;
    (void)ws_size; (void)n_in;

    hipMemsetAsync(d_ws, 0, zeroElems * sizeof(float), stream);

    int gmax = (NF > N ? NF : N);
    k_hist_both<<<(gmax + 255) / 256, 256, 0, stream>>>(inv, cntD, nxt, cntI, N, NF);
    k_scan_both<<<2, 1024, 0, stream>>>(cntD, rowstartD, MD, cntI, rowstart, MO);
    k_fill_both<<<(gmax + 255) / 256, 256, 0, stream>>>(inv, rowstartD, cursorD, csrD,
                                                        nxt, cur, rowstart, cursor,
                                                        csrAB, N, NF);

    // front MLP path (TLP-rich pool, then dense MLPs at full occupancy)
    k_downsum<<<(MD + 3) / 4, 256, 0, stream>>>(feat, csrD, rowstartD, cntD, dsum, MD);
    k_mlp64<<<2048, 256, 0, stream>>>(dsum, W1, b1, t1, ssum1, ssq1, MD);
    k_fold<<<1, 64, 0, stream>>>(ssum1, ssq1, g1, be1, W2, b2, Wp2, bp2, MD, 64);
    k_mlp64<<<2048, 256, 0, stream>>>(t1, Wp2, bp2, t2, ssum2, ssq2, MD);
    k_fold_packed<<<1, 128, 0, stream>>>(ssum2, ssq2, g2, be2, W3, b3, P3, bp3, MD);
    k_pack<<<28, 256, 0, stream>>>(W4, W5, W_in, P1, P2, P0);

    // z2 = leaky(t2 @ Wp3 + bp3) @ W4_bot          [MD x 128], L2-resident
    k_two_gemm<<<(MD + 63) / 64, 256, 0, stream>>>(t2, P3, bp3, P1 + 16384, nullptr, z2, MD);
    // z1 = leaky(feat @ Win + bin) @ W4_top + b4   [N x 128]
    k_two_gemm<<<(N + 63) / 64, 256, 0, stream>>>(feat, P0, b_in, P1, b4, z1, N);

    // per-voxel paired gather-mean of leaky(z1+z2)
    k_gather_mean<<<(MO + 3) / 4, 256, 0, stream>>>(z1, z2, csrAB, rowstart, cntI, meanB, MO);
    // out = meanB @ W5 + b5 (masked where empty)
    k_vox2<<<(MO + 63) / 64, 256, 0, stream>>>(meanB, cntI, P2, b5, (float*)d_out, MO);
}

// Round 12
// 239.241 us; speedup vs baseline: 1.3512x; 1.3512x over previous
//
#include <hip/hip_runtime.h>
#include <hip/hip_bf16.h>

#define NEG_SLOPE 0.1f
#define BN_EPS 1e-5f
#define MDV 25000

typedef __bf16 bf16_t;
typedef bf16_t bf16x8 __attribute__((ext_vector_type(8)));
typedef bf16_t bf16x4 __attribute__((ext_vector_type(4)));
typedef float f32x4 __attribute__((ext_vector_type(4)));

__device__ __forceinline__ float leaky(float x) { return x >= 0.0f ? x : NEG_SLOPE * x; }

// ---------------------------------------------------------------------------
// histogram both index arrays in one pass
__global__ void k_hist_both(const int* __restrict__ inv, int* __restrict__ cntD,
                            const int* __restrict__ nxt, int* __restrict__ cntI,
                            int N, int NF) {
    int f = blockIdx.x * 256 + threadIdx.x;
    if (f < N) atomicAdd(&cntD[inv[f]], 1);
    if (f < NF) atomicAdd(&cntI[nxt[f]], 1);
}

// ---------------------------------------------------------------------------
// grain scan: block0 scans cntD[MD]->rowstartD, block1 scans cntI[MO]->rowstart
__global__ __launch_bounds__(1024) void k_scan_both(
        const int* __restrict__ cntD, int* __restrict__ rowstartD, int MD,
        const int* __restrict__ cntI, int* __restrict__ rowstart, int MO) {
    const int* in; int* o1; int M;
    if (blockIdx.x == 0) { in = cntD; o1 = rowstartD; M = MD; }
    else                 { in = cntI; o1 = rowstart;  M = MO; }
    int t = threadIdx.x;
    int T = (M + 1023) >> 10;
    int base = t * T;
    int s1 = 0;
    for (int i = 0; i < T; i++) {
        int idx = base + i;
        s1 += (idx < M) ? in[idx] : 0;
    }
    __shared__ int sa[1024], sb[1024];
    sa[t] = s1;
    __syncthreads();
    int *p = sa, *q = sb;
    for (int off = 1; off < 1024; off <<= 1) {
        int v1 = p[t] + ((t >= off) ? p[t - off] : 0);
        q[t] = v1;
        __syncthreads();
        int* tmp = p; p = q; q = tmp;
    }
    int run1 = p[t] - s1;   // exclusive prefix of this thread's grain
    for (int i = 0; i < T; i++) {
        int idx = base + i;
        if (idx < M) {
            o1[idx] = run1;
            run1 += in[idx];
        }
    }
    if (t == 1023) o1[M] = run1;
}

// ---------------------------------------------------------------------------
// fill both CSR lists; csrD holds f; csrAB holds (cur[f], inv[cur[f]]) packed
__global__ void k_fill_both(const int* __restrict__ inv, const int* __restrict__ rowstartD,
                            int* __restrict__ cursorD, int* __restrict__ csrD,
                            const int* __restrict__ nxt, const int* __restrict__ cur,
                            const int* __restrict__ rowstart, int* __restrict__ cursor,
                            int2* __restrict__ csrAB, int N, int NF) {
    int f = blockIdx.x * 256 + threadIdx.x;
    if (f < N) {
        int v = inv[f];
        int pos = atomicAdd(&cursorD[v], 1);
        csrD[rowstartD[v] + pos] = f;
    }
    if (f < NF) {
        int v = nxt[f];
        int pos = atomicAdd(&cursor[v], 1);
        int c = cur[f];
        csrAB[rowstart[v] + pos] = make_int2(c, inv[c]);
    }
}

// ---------------------------------------------------------------------------
// voxel mean pooling via CSR gather: one wave per voxel, x2 unrolled loads
__global__ __launch_bounds__(256) void k_downsum(
        const float* __restrict__ feat, const int* __restrict__ csrD,
        const int* __restrict__ rowstartD, const int* __restrict__ cntD,
        float* __restrict__ dsum, int MD) {
    int w = threadIdx.x >> 6, l = threadIdx.x & 63;
    int vox = blockIdx.x * 4 + w;
    if (vox >= MD) return;
    int cnt = cntD[vox];
    int start = rowstartD[vox];
    float s = 0.f;
    int p = 0;
    for (; p + 2 <= cnt; p += 2) {
        int r0 = csrD[start + p];
        int r1 = csrD[start + p + 1];
        s += feat[(size_t)r0 * 64 + l] + feat[(size_t)r1 * 64 + l];
    }
    if (p < cnt) s += feat[(size_t)csrD[start + p] * 64 + l];
    dsum[(size_t)vox * 64 + l] = s / fmaxf((float)cnt, 1.0f);
}

// ---------------------------------------------------------------------------
// k_mfma_bn: out[M,64] f32 = leaky(in[M,64] @ P[64,64] + bias), plus BN stats
// (column sum/sumsq) via register butterfly + 1 atomic pair per (block, col).
// block = 64 rows, 4 waves; wave w owns cols [w*16, w*16+16).
__global__ __launch_bounds__(256) void k_mfma_bn(
        const float* __restrict__ in, const bf16_t* __restrict__ Pb,
        const float* __restrict__ bias, float* __restrict__ out,
        float* __restrict__ ssum, float* __restrict__ ssq, int M) {
    __shared__ bf16_t A[64 * 64];     // 8 KB
    int tid = threadIdx.x;
    int base = blockIdx.x * 64;
    int valid = M - base; if (valid > 64) valid = 64;

    {   // stage A: thread covers row=tid>>2, 16 cols, f32->bf16, swizzled
        int r = tid >> 2, q = tid & 3;
        float4 v[4];
        if (r < valid) {
            const float4* src = reinterpret_cast<const float4*>(in + (size_t)(base + r) * 64 + q * 16);
#pragma unroll
            for (int i = 0; i < 4; i++) v[i] = src[i];
        } else {
#pragma unroll
            for (int i = 0; i < 4; i++) v[i] = make_float4(0.f, 0.f, 0.f, 0.f);
        }
        bf16x8 h0, h1;
#pragma unroll
        for (int i = 0; i < 2; i++) {
            h0[i * 4 + 0] = (bf16_t)v[i].x; h0[i * 4 + 1] = (bf16_t)v[i].y;
            h0[i * 4 + 2] = (bf16_t)v[i].z; h0[i * 4 + 3] = (bf16_t)v[i].w;
            h1[i * 4 + 0] = (bf16_t)v[2 + i].x; h1[i * 4 + 1] = (bf16_t)v[2 + i].y;
            h1[i * 4 + 2] = (bf16_t)v[2 + i].z; h1[i * 4 + 3] = (bf16_t)v[2 + i].w;
        }
        int xa = (r & 7) << 3;
        *reinterpret_cast<bf16x8*>(&A[r * 64 + ((q * 16) ^ xa)]) = h0;
        *reinterpret_cast<bf16x8*>(&A[r * 64 + ((q * 16 + 8) ^ xa)]) = h1;
    }
    __syncthreads();

    int w = tid >> 6, l = tid & 63;
    int lg = l >> 4, lr = l & 15;
    int xr = (lr & 7) << 3;
    int col = w * 16 + lr;

    f32x4 acc[4];
    float bv = bias[col];
#pragma unroll
    for (int m = 0; m < 4; m++) acc[m] = (f32x4){bv, bv, bv, bv};
#pragma unroll
    for (int s = 0; s < 2; s++) {
        bf16x8 b = *reinterpret_cast<const bf16x8*>(Pb + ((size_t)((s * 4 + w) * 64 + l)) * 8);
#pragma unroll
        for (int m = 0; m < 4; m++) {
            bf16x8 a = *reinterpret_cast<const bf16x8*>(&A[(m * 16 + lr) * 64 + (((s * 4 + lg) * 8) ^ xr)]);
            acc[m] = __builtin_amdgcn_mfma_f32_16x16x32_bf16(a, b, acc[m], 0, 0, 0);
        }
    }

    float cs = 0.f, cq = 0.f;
#pragma unroll
    for (int m = 0; m < 4; m++) {
#pragma unroll
        for (int rr = 0; rr < 4; rr++) {
            int row = m * 16 + lg * 4 + rr;
            float val = leaky(acc[m][rr]);
            if (row < valid) {
                out[(size_t)(base + row) * 64 + col] = val;
                cs += val;
                cq += val * val;
            }
        }
    }
    cs += __shfl_xor(cs, 16); cs += __shfl_xor(cs, 32);
    cq += __shfl_xor(cq, 16); cq += __shfl_xor(cq, 32);
    if (lg == 0) {
        atomicAdd(&ssum[col], cs);
        atomicAdd(&ssq[col], cq);
    }
}

// ---------------------------------------------------------------------------
// fold BatchNorm into the next layer's weights; emit bf16 MFMA-B packed P
// (64-wide pack: sn=s*4+n) and folded bias.
__global__ void k_fold(const float* __restrict__ ssum, const float* __restrict__ ssq,
                       const float* __restrict__ g, const float* __restrict__ be,
                       const float* __restrict__ W, const float* __restrict__ b,
                       bf16_t* __restrict__ Pp, float* __restrict__ bp, int M) {
    int j = threadIdx.x;   // 0..63 output column
    if (j >= 64) return;
    float fM = (float)M;
    float accb = b[j];
    int n = j >> 4, jr = j & 15;
    for (int k = 0; k < 64; k++) {
        float mu = ssum[k] / fM;
        float var = ssq[k] / fM - mu * mu;
        float rstd = rsqrtf(var + BN_EPS);
        float ak = g[k] * rstd;
        float ck = be[k] - mu * ak;
        float w = W[k * 64 + j];
        accb = fmaf(ck, w, accb);
        int s = k >> 5, l = ((k >> 3) & 3) * 16 + jr, jj = k & 7;
        Pp[((size_t)((s * 4 + n) * 64 + l)) * 8 + jj] = (bf16_t)(ak * w);
    }
    bp[j] = accb;
}

// ---------------------------------------------------------------------------
// fold BN2 into W3 [64x128], writing bf16 MFMA-B packed fragments directly
__global__ void k_fold_packed(const float* __restrict__ ssum, const float* __restrict__ ssq,
                              const float* __restrict__ g, const float* __restrict__ be,
                              const float* __restrict__ W, const float* __restrict__ b,
                              bf16_t* __restrict__ P, float* __restrict__ bp, int M) {
    int j = threadIdx.x;   // 0..127 output column
    if (j >= 128) return;
    float fM = (float)M;
    float accb = b[j];
    int n = j >> 4, jr = j & 15;
    for (int k = 0; k < 64; k++) {
        float mu = ssum[k] / fM;
        float var = ssq[k] / fM - mu * mu;
        float rstd = rsqrtf(var + BN_EPS);
        float ak = g[k] * rstd;
        float ck = be[k] - mu * ak;
        float w = W[k * 128 + j];
        accb = fmaf(ck, w, accb);
        int s = k >> 5, l = ((k >> 3) & 3) * 16 + jr, jj = k & 7;
        P[((size_t)((s * 8 + n) * 64 + l)) * 8 + jj] = (bf16_t)(ak * w);
    }
    bp[j] = accb;
}

// ---------------------------------------------------------------------------
// Pack W4/W5/W_in (128-wide) and W1 (64-wide) into bf16 MFMA-B fragment order
__global__ void k_pack(const float* __restrict__ W4, const float* __restrict__ W5,
                       const float* __restrict__ Win, const float* __restrict__ W1,
                       bf16_t* __restrict__ P1, bf16_t* __restrict__ P2,
                       bf16_t* __restrict__ P0, bf16_t* __restrict__ P4) {
    int tid = blockIdx.x * 256 + threadIdx.x;
    if (tid < 7168) {   // 128-wide packs
        const float* W; bf16_t* P; int t;
        if (tid < 4096)      { W = W4;  P = P1; t = tid; }
        else if (tid < 6144) { W = W5;  P = P2; t = tid - 4096; }
        else                 { W = Win; P = P0; t = tid - 6144; }
        int l = t & 63;
        int sn = t >> 6;
        int col = (sn & 7) * 16 + (l & 15);
        int k0 = (sn >> 3) * 32 + (l >> 4) * 8;
        bf16_t* dst = P + (size_t)t * 8;
#pragma unroll
        for (int j = 0; j < 8; j++) dst[j] = (bf16_t)W[(size_t)(k0 + j) * 128 + col];
    } else if (tid < 7680) {   // W1 [64x64], 64-wide pack (sn = s*4+n)
        int t = tid - 7168;
        int l = t & 63;
        int sn = t >> 6;   // 0..7
        int col = (sn & 3) * 16 + (l & 15);
        int k0 = (sn >> 2) * 32 + (l >> 4) * 8;
        bf16_t* dst = P4 + (size_t)t * 8;
#pragma unroll
        for (int j = 0; j < 8; j++) dst[j] = (bf16_t)W1[(size_t)(k0 + j) * 64 + col];
    }
}

// ---------------------------------------------------------------------------
// k_two_gemm: out[M,128] = leaky(in[M,64] @ Pa + ba) @ Pb (+ bb)   (bf16 out)
__global__ __launch_bounds__(256) void k_two_gemm(
        const float* __restrict__ in, const bf16_t* __restrict__ Pa,
        const float* __restrict__ ba, const bf16_t* __restrict__ Pb,
        const float* __restrict__ bb, bf16_t* __restrict__ out, int M) {
    __shared__ bf16_t A[64 * 64];     // 8 KB
    __shared__ bf16_t C[64 * 128];    // 16 KB
    int tid = threadIdx.x;
    int base = blockIdx.x * 64;
    int valid = M - base; if (valid > 64) valid = 64;

    {   // stage A: thread covers row=tid>>2, 16 cols, f32->bf16, swizzled
        int r = tid >> 2, q = tid & 3;
        float4 v[4];
        if (r < valid) {
            const float4* src = reinterpret_cast<const float4*>(in + (size_t)(base + r) * 64 + q * 16);
#pragma unroll
            for (int i = 0; i < 4; i++) v[i] = src[i];
        } else {
#pragma unroll
            for (int i = 0; i < 4; i++) v[i] = make_float4(0.f, 0.f, 0.f, 0.f);
        }
        bf16x8 h0, h1;
#pragma unroll
        for (int i = 0; i < 2; i++) {
            h0[i * 4 + 0] = (bf16_t)v[i].x; h0[i * 4 + 1] = (bf16_t)v[i].y;
            h0[i * 4 + 2] = (bf16_t)v[i].z; h0[i * 4 + 3] = (bf16_t)v[i].w;
            h1[i * 4 + 0] = (bf16_t)v[2 + i].x; h1[i * 4 + 1] = (bf16_t)v[2 + i].y;
            h1[i * 4 + 2] = (bf16_t)v[2 + i].z; h1[i * 4 + 3] = (bf16_t)v[2 + i].w;
        }
        int xa = (r & 7) << 3;
        *reinterpret_cast<bf16x8*>(&A[r * 64 + ((q * 16) ^ xa)]) = h0;
        *reinterpret_cast<bf16x8*>(&A[r * 64 + ((q * 16 + 8) ^ xa)]) = h1;
    }
    __syncthreads();

    int w = tid >> 6, l = tid & 63;
    int lg = l >> 4, lr = l & 15;
    int xr = (lr & 7) << 3;

    // GEMM a: K=64 (2 k-steps), acc init ba, leaky -> C
    f32x4 acc[4][2];
#pragma unroll
    for (int t = 0; t < 2; t++) {
        float bv = ba[w * 32 + t * 16 + lr];
#pragma unroll
        for (int m = 0; m < 4; m++) acc[m][t] = (f32x4){bv, bv, bv, bv};
    }
#pragma unroll
    for (int s = 0; s < 2; s++) {
        bf16x8 a[4];
#pragma unroll
        for (int m = 0; m < 4; m++)
            a[m] = *reinterpret_cast<const bf16x8*>(&A[(m * 16 + lr) * 64 + (((s * 4 + lg) * 8) ^ xr)]);
#pragma unroll
        for (int t = 0; t < 2; t++) {
            bf16x8 b = *reinterpret_cast<const bf16x8*>(Pa + ((size_t)(s * 8 + w * 2 + t) * 64 + l) * 8);
#pragma unroll
            for (int m = 0; m < 4; m++)
                acc[m][t] = __builtin_amdgcn_mfma_f32_16x16x32_bf16(a[m], b, acc[m][t], 0, 0, 0);
        }
    }
#pragma unroll
    for (int m = 0; m < 4; m++)
#pragma unroll
        for (int t = 0; t < 2; t++)
#pragma unroll
            for (int rr = 0; rr < 4; rr++) {
                int row = m * 16 + lg * 4 + rr;
                int col = w * 32 + t * 16 + lr;
                C[row * 128 + (col ^ ((row & 7) << 3))] = (bf16_t)leaky(acc[m][t][rr]);
            }
    __syncthreads();

    // GEMM b: K=128 (4 k-steps), acc init bb (or 0)
    f32x4 acc2[4][2];
#pragma unroll
    for (int t = 0; t < 2; t++) {
        float bv = bb ? bb[w * 32 + t * 16 + lr] : 0.0f;
#pragma unroll
        for (int m = 0; m < 4; m++) acc2[m][t] = (f32x4){bv, bv, bv, bv};
    }
#pragma unroll
    for (int s = 0; s < 4; s++) {
        bf16x8 a[4];
#pragma unroll
        for (int m = 0; m < 4; m++)
            a[m] = *reinterpret_cast<const bf16x8*>(&C[(m * 16 + lr) * 128 + ((s * 32 + lg * 8) ^ xr)]);
#pragma unroll
        for (int t = 0; t < 2; t++) {
            bf16x8 b = *reinterpret_cast<const bf16x8*>(Pb + ((size_t)(s * 8 + w * 2 + t) * 64 + l) * 8);
#pragma unroll
            for (int m = 0; m < 4; m++)
                acc2[m][t] = __builtin_amdgcn_mfma_f32_16x16x32_bf16(a[m], b, acc2[m][t], 0, 0, 0);
        }
    }
    __syncthreads();   // all C reads complete before overwrite

    // overwrite C with acc2 (no activation), then coalesced 16B write-out
#pragma unroll
    for (int m = 0; m < 4; m++)
#pragma unroll
        for (int t = 0; t < 2; t++)
#pragma unroll
            for (int rr = 0; rr < 4; rr++) {
                int row = m * 16 + lg * 4 + rr;
                int col = w * 32 + t * 16 + lr;
                C[row * 128 + (col ^ ((row & 7) << 3))] = (bf16_t)acc2[m][t][rr];
            }
    __syncthreads();
#pragma unroll
    for (int i = 0; i < 4; i++) {
        int u = tid + i * 256;
        int row = u >> 4, seg = u & 15;
        if (row < valid) {
            bf16x8 val = *reinterpret_cast<const bf16x8*>(&C[row * 128 + ((seg * 8) ^ ((row & 7) << 3))]);
            *reinterpret_cast<bf16x8*>(&out[(size_t)(base + row) * 128 + seg * 8]) = val;
        }
    }
}

// ---------------------------------------------------------------------------
// k_gather_mean v2: one wave per output voxel; 2 points per instruction
// (lanes 0-31 cover point p, lanes 32-63 point p+1; bf16x4 per lane), x2 unroll.
__global__ __launch_bounds__(256) void k_gather_mean(
        const bf16_t* __restrict__ z1, const bf16_t* __restrict__ z2,
        const int2* __restrict__ csrAB, const int* __restrict__ rowstart,
        const int* __restrict__ cntI, bf16_t* __restrict__ meanB, int MO) {
    int w = threadIdx.x >> 6, l = threadIdx.x & 63;
    int half = l >> 5, sub = l & 31;
    int v = blockIdx.x * 4 + w;
    if (v >= MO) return;
    int cnt = cntI[v];
    int start = rowstart[v];
    float s[4] = {0.f, 0.f, 0.f, 0.f};
    int p = 0;
    for (; p + 4 <= cnt; p += 4) {
        int2 ea = csrAB[start + p + half];
        int2 eb = csrAB[start + p + 2 + half];
        bf16x4 za0 = *reinterpret_cast<const bf16x4*>(&z1[(size_t)ea.x * 128 + sub * 4]);
        bf16x4 zb0 = *reinterpret_cast<const bf16x4*>(&z2[(size_t)ea.y * 128 + sub * 4]);
        bf16x4 za1 = *reinterpret_cast<const bf16x4*>(&z1[(size_t)eb.x * 128 + sub * 4]);
        bf16x4 zb1 = *reinterpret_cast<const bf16x4*>(&z2[(size_t)eb.y * 128 + sub * 4]);
#pragma unroll
        for (int j = 0; j < 4; j++) {
            s[j] += leaky((float)za0[j] + (float)zb0[j]);
            s[j] += leaky((float)za1[j] + (float)zb1[j]);
        }
    }
    for (; p + 2 <= cnt; p += 2) {
        int2 e = csrAB[start + p + half];
        bf16x4 za = *reinterpret_cast<const bf16x4*>(&z1[(size_t)e.x * 128 + sub * 4]);
        bf16x4 zb = *reinterpret_cast<const bf16x4*>(&z2[(size_t)e.y * 128 + sub * 4]);
#pragma unroll
        for (int j = 0; j < 4; j++) s[j] += leaky((float)za[j] + (float)zb[j]);
    }
    if (p < cnt && half == 0) {
        int2 e = csrAB[start + p];
        bf16x4 za = *reinterpret_cast<const bf16x4*>(&z1[(size_t)e.x * 128 + sub * 4]);
        bf16x4 zb = *reinterpret_cast<const bf16x4*>(&z2[(size_t)e.y * 128 + sub * 4]);
#pragma unroll
        for (int j = 0; j < 4; j++) s[j] += leaky((float)za[j] + (float)zb[j]);
    }
    float sc = (cnt > 0) ? (1.0f / (float)cnt) : 0.0f;
    bf16x4 mv;
#pragma unroll
    for (int j = 0; j < 4; j++) {
        s[j] += __shfl_xor(s[j], 32);
        mv[j] = (bf16_t)(s[j] * sc);
    }
    if (half == 0)
        *reinterpret_cast<bf16x4*>(&meanB[(size_t)v * 128 + sub * 4]) = mv;
}

// ---------------------------------------------------------------------------
// k_vox2: out[MO,128] f32 = meanB[MO,128] @ P2 + b5, masked to 0 where cnt==0
__global__ __launch_bounds__(256) void k_vox2(
        const bf16_t* __restrict__ meanB, const int* __restrict__ cntI,
        const bf16_t* __restrict__ P2, const float* __restrict__ b5,
        float* __restrict__ outp, int MO) {
    int tid = threadIdx.x;
    int base = blockIdx.x * 64;
    int w = tid >> 6, l = tid & 63;
    int lg = l >> 4, lr = l & 15;
    f32x4 acc[4][2];
#pragma unroll
    for (int t = 0; t < 2; t++) {
        float bv = b5[w * 32 + t * 16 + lr];
#pragma unroll
        for (int m = 0; m < 4; m++) acc[m][t] = (f32x4){bv, bv, bv, bv};
    }
#pragma unroll
    for (int s = 0; s < 4; s++) {
        bf16x8 a[4];
#pragma unroll
        for (int m = 0; m < 4; m++) {
            int row = base + m * 16 + lr;
            a[m] = *reinterpret_cast<const bf16x8*>(&meanB[(size_t)row * 128 + (s * 4 + lg) * 8]);
        }
#pragma unroll
        for (int t = 0; t < 2; t++) {
            bf16x8 b = *reinterpret_cast<const bf16x8*>(P2 + ((size_t)(s * 8 + w * 2 + t) * 64 + l) * 8);
#pragma unroll
            for (int m = 0; m < 4; m++)
                acc[m][t] = __builtin_amdgcn_mfma_f32_16x16x32_bf16(a[m], b, acc[m][t], 0, 0, 0);
        }
    }
#pragma unroll
    for (int m = 0; m < 4; m++)
#pragma unroll
        for (int t = 0; t < 2; t++)
#pragma unroll
            for (int rr = 0; rr < 4; rr++) {
                int row = base + m * 16 + lg * 4 + rr;
                if (row < MO) {
                    float val = (cntI[row] > 0) ? acc[m][t][rr] : 0.0f;
                    outp[(size_t)row * 128 + w * 32 + t * 16 + lr] = val;
                }
            }
}

// ---------------------------------------------------------------------------
extern "C" void kernel_launch(void* const* d_in, const int* in_sizes, int n_in,
                              void* d_out, int out_size, void* d_ws, size_t ws_size,
                              hipStream_t stream) {
    const float* feat = (const float*)d_in[0];
    const int*   inv  = (const int*)d_in[1];
    const int*   cur  = (const int*)d_in[2];
    const int*   nxt  = (const int*)d_in[3];
    const float* W_in = (const float*)d_in[6];
    const float* b_in = (const float*)d_in[7];
    const float* W1   = (const float*)d_in[8];
    const float* b1   = (const float*)d_in[9];
    const float* g1   = (const float*)d_in[10];
    const float* be1  = (const float*)d_in[11];
    const float* W2   = (const float*)d_in[12];
    const float* b2   = (const float*)d_in[13];
    const float* g2   = (const float*)d_in[14];
    const float* be2  = (const float*)d_in[15];
    const float* W3   = (const float*)d_in[16];
    const float* b3   = (const float*)d_in[17];
    const float* W4   = (const float*)d_in[18];
    const float* b4   = (const float*)d_in[19];
    const float* W5   = (const float*)d_in[20];
    const float* b5   = (const float*)d_in[21];

    const int N  = in_sizes[0] / 64;
    const int NF = in_sizes[2];
    const int MO = out_size / 128;
    const int MD = MDV;   // n_down (device scalar; fixed problem size)

    float* ws = (float*)d_ws;
    size_t off = 0;
    // ---- zeroed region (stats + counters only) ----
    float* ssum1 = ws + off; off += 64;
    float* ssq1  = ws + off; off += 64;
    float* ssum2 = ws + off; off += 64;
    float* ssq2  = ws + off; off += 64;
    int* cntD    = (int*)(ws + off); off += (size_t)MD;
    int* cursorD = (int*)(ws + off); off += (size_t)MD;
    int* cntI    = (int*)(ws + off); off += (size_t)MO;
    int* cursor  = (int*)(ws + off); off += (size_t)MO;
    size_t zeroElems = off;
    // ---- non-zeroed ----
    float* dsum = ws + off; off += (size_t)MD * 64;
    float* t1   = ws + off; off += (size_t)MD * 64;
    float* t2   = ws + off; off += (size_t)MD * 64;
    float* bp2  = ws + off; off += 64;
    float* bp3  = ws + off; off += 128;
    int* rowstartD = (int*)(ws + off); off += (size_t)MD + 1;
    int* rowstart  = (int*)(ws + off); off += (size_t)MO + 1;
    int* csrD      = (int*)(ws + off); off += (size_t)N;
    off = (off + 1) & ~(size_t)1;   // 8B align for int2
    int2* csrAB    = (int2*)(ws + off); off += (size_t)NF * 2;
    bf16_t* bws = (bf16_t*)(ws + off);
    size_t boff = 0;
    bf16_t* z1    = bws + boff; boff += (size_t)N * 128;
    bf16_t* z2    = bws + boff; boff += (size_t)MD * 128;
    bf16_t* meanB = bws + boff; boff += (size_t)MO * 128 + 4096;  // +slack for tail OOB reads
    bf16_t* P0    = bws + boff; boff += 8192;
    bf16_t* P1    = bws + boff; boff += 32768;
    bf16_t* P2    = bws + boff; boff += 16384;
    bf16_t* P3    = bws + boff; boff += 8192;
    bf16_t* P4    = bws + boff; boff += 4096;
    bf16_t* P5    = bws + boff; boff += 4096;
    (void)ws_size; (void)n_in;

    hipMemsetAsync(d_ws, 0, zeroElems * sizeof(float), stream);

    int gmax = (NF > N ? NF : N);
    k_hist_both<<<(gmax + 255) / 256, 256, 0, stream>>>(inv, cntD, nxt, cntI, N, NF);
    k_scan_both<<<2, 1024, 0, stream>>>(cntD, rowstartD, MD, cntI, rowstart, MO);
    k_fill_both<<<(gmax + 255) / 256, 256, 0, stream>>>(inv, rowstartD, cursorD, csrD,
                                                        nxt, cur, rowstart, cursor,
                                                        csrAB, N, NF);
    k_pack<<<30, 256, 0, stream>>>(W4, W5, W_in, W1, P1, P2, P0, P4);

    // front MLP path: pool -> MFMA layer1 (+stats) -> fold -> MFMA layer2 (+stats) -> fold
    k_downsum<<<(MD + 3) / 4, 256, 0, stream>>>(feat, csrD, rowstartD, cntD, dsum, MD);
    k_mfma_bn<<<(MD + 63) / 64, 256, 0, stream>>>(dsum, P4, b1, t1, ssum1, ssq1, MD);
    k_fold<<<1, 64, 0, stream>>>(ssum1, ssq1, g1, be1, W2, b2, P5, bp2, MD);
    k_mfma_bn<<<(MD + 63) / 64, 256, 0, stream>>>(t1, P5, bp2, t2, ssum2, ssq2, MD);
    k_fold_packed<<<1, 128, 0, stream>>>(ssum2, ssq2, g2, be2, W3, b3, P3, bp3, MD);

    // z2 = leaky(t2 @ Wp3 + bp3) @ W4_bot          [MD x 128], L2-resident
    k_two_gemm<<<(MD + 63) / 64, 256, 0, stream>>>(t2, P3, bp3, P1 + 16384, nullptr, z2, MD);
    // z1 = leaky(feat @ Win + bin) @ W4_top + b4   [N x 128]
    k_two_gemm<<<(N + 63) / 64, 256, 0, stream>>>(feat, P0, b_in, P1, b4, z1, N);

    // per-voxel paired gather-mean of leaky(z1+z2)
    k_gather_mean<<<(MO + 3) / 4, 256, 0, stream>>>(z1, z2, csrAB, rowstart, cntI, meanB, MO);
    // out = meanB @ W5 + b5 (masked where empty)
    k_vox2<<<(MO + 63) / 64, 256, 0, stream>>>(meanB, cntI, P2, b5, (float*)d_out, MO);
}

// Round 13
// 239.177 us; speedup vs baseline: 1.3515x; 1.0003x over previous
//
#include <hip/hip_runtime.h>
#include <hip/hip_bf16.h>

#define NEG_SLOPE 0.1f
#define BN_EPS 1e-5f
#define MDV 25000

typedef __bf16 bf16_t;
typedef bf16_t bf16x8 __attribute__((ext_vector_type(8)));
typedef bf16_t bf16x4 __attribute__((ext_vector_type(4)));
typedef float f32x4 __attribute__((ext_vector_type(4)));

__device__ __forceinline__ float leaky(float x) { return x >= 0.0f ? x : NEG_SLOPE * x; }

// ---------------------------------------------------------------------------
// fast workspace zero (replaces 41us runtime fillBuffer for 400KB)
__global__ void k_zero(int4* __restrict__ p, int n4) {
    int i = blockIdx.x * 256 + threadIdx.x;
    if (i < n4) p[i] = make_int4(0, 0, 0, 0);
}

// ---------------------------------------------------------------------------
// histogram both index arrays in one pass
__global__ void k_hist_both(const int* __restrict__ inv, int* __restrict__ cntD,
                            const int* __restrict__ nxt, int* __restrict__ cntI,
                            int N, int NF) {
    int f = blockIdx.x * 256 + threadIdx.x;
    if (f < N) atomicAdd(&cntD[inv[f]], 1);
    if (f < NF) atomicAdd(&cntI[nxt[f]], 1);
}

// ---------------------------------------------------------------------------
// grain scan: block0 scans cntD[MD]->rowstartD, block1 scans cntI[MO]->rowstart
__global__ __launch_bounds__(1024) void k_scan_both(
        const int* __restrict__ cntD, int* __restrict__ rowstartD, int MD,
        const int* __restrict__ cntI, int* __restrict__ rowstart, int MO) {
    const int* in; int* o1; int M;
    if (blockIdx.x == 0) { in = cntD; o1 = rowstartD; M = MD; }
    else                 { in = cntI; o1 = rowstart;  M = MO; }
    int t = threadIdx.x;
    int T = (M + 1023) >> 10;
    int base = t * T;
    int s1 = 0;
    for (int i = 0; i < T; i++) {
        int idx = base + i;
        s1 += (idx < M) ? in[idx] : 0;
    }
    __shared__ int sa[1024], sb[1024];
    sa[t] = s1;
    __syncthreads();
    int *p = sa, *q = sb;
    for (int off = 1; off < 1024; off <<= 1) {
        int v1 = p[t] + ((t >= off) ? p[t - off] : 0);
        q[t] = v1;
        __syncthreads();
        int* tmp = p; p = q; q = tmp;
    }
    int run1 = p[t] - s1;   // exclusive prefix of this thread's grain
    for (int i = 0; i < T; i++) {
        int idx = base + i;
        if (idx < M) {
            o1[idx] = run1;
            run1 += in[idx];
        }
    }
    if (t == 1023) o1[M] = run1;
}

// ---------------------------------------------------------------------------
// fill both CSR lists; csrD holds f; csrAB holds (cur[f], inv[cur[f]]) packed
__global__ void k_fill_both(const int* __restrict__ inv, const int* __restrict__ rowstartD,
                            int* __restrict__ cursorD, int* __restrict__ csrD,
                            const int* __restrict__ nxt, const int* __restrict__ cur,
                            const int* __restrict__ rowstart, int* __restrict__ cursor,
                            int2* __restrict__ csrAB, int N, int NF) {
    int f = blockIdx.x * 256 + threadIdx.x;
    if (f < N) {
        int v = inv[f];
        int pos = atomicAdd(&cursorD[v], 1);
        csrD[rowstartD[v] + pos] = f;
    }
    if (f < NF) {
        int v = nxt[f];
        int pos = atomicAdd(&cursor[v], 1);
        int c = cur[f];
        csrAB[rowstart[v] + pos] = make_int2(c, inv[c]);
    }
}

// ---------------------------------------------------------------------------
// voxel mean pooling via CSR gather: one wave per voxel, x2 unrolled loads
__global__ __launch_bounds__(256) void k_downsum(
        const float* __restrict__ feat, const int* __restrict__ csrD,
        const int* __restrict__ rowstartD, const int* __restrict__ cntD,
        float* __restrict__ dsum, int MD) {
    int w = threadIdx.x >> 6, l = threadIdx.x & 63;
    int vox = blockIdx.x * 4 + w;
    if (vox >= MD) return;
    int cnt = cntD[vox];
    int start = rowstartD[vox];
    float s = 0.f;
    int p = 0;
    for (; p + 2 <= cnt; p += 2) {
        int r0 = csrD[start + p];
        int r1 = csrD[start + p + 1];
        s += feat[(size_t)r0 * 64 + l] + feat[(size_t)r1 * 64 + l];
    }
    if (p < cnt) s += feat[(size_t)csrD[start + p] * 64 + l];
    dsum[(size_t)vox * 64 + l] = s / fmaxf((float)cnt, 1.0f);
}

// ---------------------------------------------------------------------------
// k_mfma_bn: out[M,64] f32 = leaky(in[M,64] @ P[64,64] + bias), plus BN stats
// (column sum/sumsq) via register butterfly + 1 atomic pair per (block, col).
// block = 64 rows, 4 waves; wave w owns cols [w*16, w*16+16).
__global__ __launch_bounds__(256) void k_mfma_bn(
        const float* __restrict__ in, const bf16_t* __restrict__ Pb,
        const float* __restrict__ bias, float* __restrict__ out,
        float* __restrict__ ssum, float* __restrict__ ssq, int M) {
    __shared__ bf16_t A[64 * 64];     // 8 KB
    int tid = threadIdx.x;
    int base = blockIdx.x * 64;
    int valid = M - base; if (valid > 64) valid = 64;

    {   // stage A: thread covers row=tid>>2, 16 cols, f32->bf16, swizzled
        int r = tid >> 2, q = tid & 3;
        float4 v[4];
        if (r < valid) {
            const float4* src = reinterpret_cast<const float4*>(in + (size_t)(base + r) * 64 + q * 16);
#pragma unroll
            for (int i = 0; i < 4; i++) v[i] = src[i];
        } else {
#pragma unroll
            for (int i = 0; i < 4; i++) v[i] = make_float4(0.f, 0.f, 0.f, 0.f);
        }
        bf16x8 h0, h1;
#pragma unroll
        for (int i = 0; i < 2; i++) {
            h0[i * 4 + 0] = (bf16_t)v[i].x; h0[i * 4 + 1] = (bf16_t)v[i].y;
            h0[i * 4 + 2] = (bf16_t)v[i].z; h0[i * 4 + 3] = (bf16_t)v[i].w;
            h1[i * 4 + 0] = (bf16_t)v[2 + i].x; h1[i * 4 + 1] = (bf16_t)v[2 + i].y;
            h1[i * 4 + 2] = (bf16_t)v[2 + i].z; h1[i * 4 + 3] = (bf16_t)v[2 + i].w;
        }
        int xa = (r & 7) << 3;
        *reinterpret_cast<bf16x8*>(&A[r * 64 + ((q * 16) ^ xa)]) = h0;
        *reinterpret_cast<bf16x8*>(&A[r * 64 + ((q * 16 + 8) ^ xa)]) = h1;
    }
    __syncthreads();

    int w = tid >> 6, l = tid & 63;
    int lg = l >> 4, lr = l & 15;
    int xr = (lr & 7) << 3;
    int col = w * 16 + lr;

    f32x4 acc[4];
    float bv = bias[col];
#pragma unroll
    for (int m = 0; m < 4; m++) acc[m] = (f32x4){bv, bv, bv, bv};
#pragma unroll
    for (int s = 0; s < 2; s++) {
        bf16x8 b = *reinterpret_cast<const bf16x8*>(Pb + ((size_t)((s * 4 + w) * 64 + l)) * 8);
#pragma unroll
        for (int m = 0; m < 4; m++) {
            bf16x8 a = *reinterpret_cast<const bf16x8*>(&A[(m * 16 + lr) * 64 + (((s * 4 + lg) * 8) ^ xr)]);
            acc[m] = __builtin_amdgcn_mfma_f32_16x16x32_bf16(a, b, acc[m], 0, 0, 0);
        }
    }

    float cs = 0.f, cq = 0.f;
#pragma unroll
    for (int m = 0; m < 4; m++) {
#pragma unroll
        for (int rr = 0; rr < 4; rr++) {
            int row = m * 16 + lg * 4 + rr;
            float val = leaky(acc[m][rr]);
            if (row < valid) {
                out[(size_t)(base + row) * 64 + col] = val;
                cs += val;
                cq += val * val;
            }
        }
    }
    cs += __shfl_xor(cs, 16); cs += __shfl_xor(cs, 32);
    cq += __shfl_xor(cq, 16); cq += __shfl_xor(cq, 32);
    if (lg == 0) {
        atomicAdd(&ssum[col], cs);
        atomicAdd(&ssq[col], cq);
    }
}

// ---------------------------------------------------------------------------
// fold BatchNorm into the next layer's weights; emit bf16 MFMA-B packed P
// (64-wide pack: sn=s*4+n) and folded bias.
__global__ void k_fold(const float* __restrict__ ssum, const float* __restrict__ ssq,
                       const float* __restrict__ g, const float* __restrict__ be,
                       const float* __restrict__ W, const float* __restrict__ b,
                       bf16_t* __restrict__ Pp, float* __restrict__ bp, int M) {
    int j = threadIdx.x;   // 0..63 output column
    if (j >= 64) return;
    float fM = (float)M;
    float accb = b[j];
    int n = j >> 4, jr = j & 15;
    for (int k = 0; k < 64; k++) {
        float mu = ssum[k] / fM;
        float var = ssq[k] / fM - mu * mu;
        float rstd = rsqrtf(var + BN_EPS);
        float ak = g[k] * rstd;
        float ck = be[k] - mu * ak;
        float w = W[k * 64 + j];
        accb = fmaf(ck, w, accb);
        int s = k >> 5, l = ((k >> 3) & 3) * 16 + jr, jj = k & 7;
        Pp[((size_t)((s * 4 + n) * 64 + l)) * 8 + jj] = (bf16_t)(ak * w);
    }
    bp[j] = accb;
}

// ---------------------------------------------------------------------------
// fold BN2 into W3 [64x128], writing bf16 MFMA-B packed fragments directly
__global__ void k_fold_packed(const float* __restrict__ ssum, const float* __restrict__ ssq,
                              const float* __restrict__ g, const float* __restrict__ be,
                              const float* __restrict__ W, const float* __restrict__ b,
                              bf16_t* __restrict__ P, float* __restrict__ bp, int M) {
    int j = threadIdx.x;   // 0..127 output column
    if (j >= 128) return;
    float fM = (float)M;
    float accb = b[j];
    int n = j >> 4, jr = j & 15;
    for (int k = 0; k < 64; k++) {
        float mu = ssum[k] / fM;
        float var = ssq[k] / fM - mu * mu;
        float rstd = rsqrtf(var + BN_EPS);
        float ak = g[k] * rstd;
        float ck = be[k] - mu * ak;
        float w = W[k * 128 + j];
        accb = fmaf(ck, w, accb);
        int s = k >> 5, l = ((k >> 3) & 3) * 16 + jr, jj = k & 7;
        P[((size_t)((s * 8 + n) * 64 + l)) * 8 + jj] = (bf16_t)(ak * w);
    }
    bp[j] = accb;
}

// ---------------------------------------------------------------------------
// Pack W4/W5/W_in (128-wide) and W1 (64-wide) into bf16 MFMA-B fragment order
__global__ void k_pack(const float* __restrict__ W4, const float* __restrict__ W5,
                       const float* __restrict__ Win, const float* __restrict__ W1,
                       bf16_t* __restrict__ P1, bf16_t* __restrict__ P2,
                       bf16_t* __restrict__ P0, bf16_t* __restrict__ P4) {
    int tid = blockIdx.x * 256 + threadIdx.x;
    if (tid < 7168) {   // 128-wide packs
        const float* W; bf16_t* P; int t;
        if (tid < 4096)      { W = W4;  P = P1; t = tid; }
        else if (tid < 6144) { W = W5;  P = P2; t = tid - 4096; }
        else                 { W = Win; P = P0; t = tid - 6144; }
        int l = t & 63;
        int sn = t >> 6;
        int col = (sn & 7) * 16 + (l & 15);
        int k0 = (sn >> 3) * 32 + (l >> 4) * 8;
        bf16_t* dst = P + (size_t)t * 8;
#pragma unroll
        for (int j = 0; j < 8; j++) dst[j] = (bf16_t)W[(size_t)(k0 + j) * 128 + col];
    } else if (tid < 7680) {   // W1 [64x64], 64-wide pack (sn = s*4+n)
        int t = tid - 7168;
        int l = t & 63;
        int sn = t >> 6;   // 0..7
        int col = (sn & 3) * 16 + (l & 15);
        int k0 = (sn >> 2) * 32 + (l >> 4) * 8;
        bf16_t* dst = P4 + (size_t)t * 8;
#pragma unroll
        for (int j = 0; j < 8; j++) dst[j] = (bf16_t)W1[(size_t)(k0 + j) * 64 + col];
    }
}

// ---------------------------------------------------------------------------
// k_two_gemm: out[M,128] = leaky(in[M,64] @ Pa + ba) @ Pb (+ bb)   (bf16 out)
__global__ __launch_bounds__(256) void k_two_gemm(
        const float* __restrict__ in, const bf16_t* __restrict__ Pa,
        const float* __restrict__ ba, const bf16_t* __restrict__ Pb,
        const float* __restrict__ bb, bf16_t* __restrict__ out, int M) {
    __shared__ bf16_t A[64 * 64];     // 8 KB
    __shared__ bf16_t C[64 * 128];    // 16 KB
    int tid = threadIdx.x;
    int base = blockIdx.x * 64;
    int valid = M - base; if (valid > 64) valid = 64;

    {   // stage A: thread covers row=tid>>2, 16 cols, f32->bf16, swizzled
        int r = tid >> 2, q = tid & 3;
        float4 v[4];
        if (r < valid) {
            const float4* src = reinterpret_cast<const float4*>(in + (size_t)(base + r) * 64 + q * 16);
#pragma unroll
            for (int i = 0; i < 4; i++) v[i] = src[i];
        } else {
#pragma unroll
            for (int i = 0; i < 4; i++) v[i] = make_float4(0.f, 0.f, 0.f, 0.f);
        }
        bf16x8 h0, h1;
#pragma unroll
        for (int i = 0; i < 2; i++) {
            h0[i * 4 + 0] = (bf16_t)v[i].x; h0[i * 4 + 1] = (bf16_t)v[i].y;
            h0[i * 4 + 2] = (bf16_t)v[i].z; h0[i * 4 + 3] = (bf16_t)v[i].w;
            h1[i * 4 + 0] = (bf16_t)v[2 + i].x; h1[i * 4 + 1] = (bf16_t)v[2 + i].y;
            h1[i * 4 + 2] = (bf16_t)v[2 + i].z; h1[i * 4 + 3] = (bf16_t)v[2 + i].w;
        }
        int xa = (r & 7) << 3;
        *reinterpret_cast<bf16x8*>(&A[r * 64 + ((q * 16) ^ xa)]) = h0;
        *reinterpret_cast<bf16x8*>(&A[r * 64 + ((q * 16 + 8) ^ xa)]) = h1;
    }
    __syncthreads();

    int w = tid >> 6, l = tid & 63;
    int lg = l >> 4, lr = l & 15;
    int xr = (lr & 7) << 3;

    // GEMM a: K=64 (2 k-steps), acc init ba, leaky -> C
    f32x4 acc[4][2];
#pragma unroll
    for (int t = 0; t < 2; t++) {
        float bv = ba[w * 32 + t * 16 + lr];
#pragma unroll
        for (int m = 0; m < 4; m++) acc[m][t] = (f32x4){bv, bv, bv, bv};
    }
#pragma unroll
    for (int s = 0; s < 2; s++) {
        bf16x8 a[4];
#pragma unroll
        for (int m = 0; m < 4; m++)
            a[m] = *reinterpret_cast<const bf16x8*>(&A[(m * 16 + lr) * 64 + (((s * 4 + lg) * 8) ^ xr)]);
#pragma unroll
        for (int t = 0; t < 2; t++) {
            bf16x8 b = *reinterpret_cast<const bf16x8*>(Pa + ((size_t)(s * 8 + w * 2 + t) * 64 + l) * 8);
#pragma unroll
            for (int m = 0; m < 4; m++)
                acc[m][t] = __builtin_amdgcn_mfma_f32_16x16x32_bf16(a[m], b, acc[m][t], 0, 0, 0);
        }
    }
#pragma unroll
    for (int m = 0; m < 4; m++)
#pragma unroll
        for (int t = 0; t < 2; t++)
#pragma unroll
            for (int rr = 0; rr < 4; rr++) {
                int row = m * 16 + lg * 4 + rr;
                int col = w * 32 + t * 16 + lr;
                C[row * 128 + (col ^ ((row & 7) << 3))] = (bf16_t)leaky(acc[m][t][rr]);
            }
    __syncthreads();

    // GEMM b: K=128 (4 k-steps), acc init bb (or 0)
    f32x4 acc2[4][2];
#pragma unroll
    for (int t = 0; t < 2; t++) {
        float bv = bb ? bb[w * 32 + t * 16 + lr] : 0.0f;
#pragma unroll
        for (int m = 0; m < 4; m++) acc2[m][t] = (f32x4){bv, bv, bv, bv};
    }
#pragma unroll
    for (int s = 0; s < 4; s++) {
        bf16x8 a[4];
#pragma unroll
        for (int m = 0; m < 4; m++)
            a[m] = *reinterpret_cast<const bf16x8*>(&C[(m * 16 + lr) * 128 + ((s * 32 + lg * 8) ^ xr)]);
#pragma unroll
        for (int t = 0; t < 2; t++) {
            bf16x8 b = *reinterpret_cast<const bf16x8*>(Pb + ((size_t)(s * 8 + w * 2 + t) * 64 + l) * 8);
#pragma unroll
            for (int m = 0; m < 4; m++)
                acc2[m][t] = __builtin_amdgcn_mfma_f32_16x16x32_bf16(a[m], b, acc2[m][t], 0, 0, 0);
        }
    }
    __syncthreads();   // all C reads complete before overwrite

    // overwrite C with acc2 (no activation), then coalesced 16B write-out
#pragma unroll
    for (int m = 0; m < 4; m++)
#pragma unroll
        for (int t = 0; t < 2; t++)
#pragma unroll
            for (int rr = 0; rr < 4; rr++) {
                int row = m * 16 + lg * 4 + rr;
                int col = w * 32 + t * 16 + lr;
                C[row * 128 + (col ^ ((row & 7) << 3))] = (bf16_t)acc2[m][t][rr];
            }
    __syncthreads();
#pragma unroll
    for (int i = 0; i < 4; i++) {
        int u = tid + i * 256;
        int row = u >> 4, seg = u & 15;
        if (row < valid) {
            bf16x8 val = *reinterpret_cast<const bf16x8*>(&C[row * 128 + ((seg * 8) ^ ((row & 7) << 3))]);
            *reinterpret_cast<bf16x8*>(&out[(size_t)(base + row) * 128 + seg * 8]) = val;
        }
    }
}

// ---------------------------------------------------------------------------
// k_gather_mean v2: one wave per output voxel; 2 points per instruction
// (lanes 0-31 cover point p, lanes 32-63 point p+1; bf16x4 per lane), x2 unroll.
__global__ __launch_bounds__(256) void k_gather_mean(
        const bf16_t* __restrict__ z1, const bf16_t* __restrict__ z2,
        const int2* __restrict__ csrAB, const int* __restrict__ rowstart,
        const int* __restrict__ cntI, bf16_t* __restrict__ meanB, int MO) {
    int w = threadIdx.x >> 6, l = threadIdx.x & 63;
    int half = l >> 5, sub = l & 31;
    int v = blockIdx.x * 4 + w;
    if (v >= MO) return;
    int cnt = cntI[v];
    int start = rowstart[v];
    float s[4] = {0.f, 0.f, 0.f, 0.f};
    int p = 0;
    for (; p + 4 <= cnt; p += 4) {
        int2 ea = csrAB[start + p + half];
        int2 eb = csrAB[start + p + 2 + half];
        bf16x4 za0 = *reinterpret_cast<const bf16x4*>(&z1[(size_t)ea.x * 128 + sub * 4]);
        bf16x4 zb0 = *reinterpret_cast<const bf16x4*>(&z2[(size_t)ea.y * 128 + sub * 4]);
        bf16x4 za1 = *reinterpret_cast<const bf16x4*>(&z1[(size_t)eb.x * 128 + sub * 4]);
        bf16x4 zb1 = *reinterpret_cast<const bf16x4*>(&z2[(size_t)eb.y * 128 + sub * 4]);
#pragma unroll
        for (int j = 0; j < 4; j++) {
            s[j] += leaky((float)za0[j] + (float)zb0[j]);
            s[j] += leaky((float)za1[j] + (float)zb1[j]);
        }
    }
    for (; p + 2 <= cnt; p += 2) {
        int2 e = csrAB[start + p + half];
        bf16x4 za = *reinterpret_cast<const bf16x4*>(&z1[(size_t)e.x * 128 + sub * 4]);
        bf16x4 zb = *reinterpret_cast<const bf16x4*>(&z2[(size_t)e.y * 128 + sub * 4]);
#pragma unroll
        for (int j = 0; j < 4; j++) s[j] += leaky((float)za[j] + (float)zb[j]);
    }
    if (p < cnt && half == 0) {
        int2 e = csrAB[start + p];
        bf16x4 za = *reinterpret_cast<const bf16x4*>(&z1[(size_t)e.x * 128 + sub * 4]);
        bf16x4 zb = *reinterpret_cast<const bf16x4*>(&z2[(size_t)e.y * 128 + sub * 4]);
#pragma unroll
        for (int j = 0; j < 4; j++) s[j] += leaky((float)za[j] + (float)zb[j]);
    }
    float sc = (cnt > 0) ? (1.0f / (float)cnt) : 0.0f;
    bf16x4 mv;
#pragma unroll
    for (int j = 0; j < 4; j++) {
        s[j] += __shfl_xor(s[j], 32);
        mv[j] = (bf16_t)(s[j] * sc);
    }
    if (half == 0)
        *reinterpret_cast<bf16x4*>(&meanB[(size_t)v * 128 + sub * 4]) = mv;
}

// ---------------------------------------------------------------------------
// k_vox2: out[MO,128] f32 = meanB[MO,128] @ P2 + b5, masked to 0 where cnt==0
__global__ __launch_bounds__(256) void k_vox2(
        const bf16_t* __restrict__ meanB, const int* __restrict__ cntI,
        const bf16_t* __restrict__ P2, const float* __restrict__ b5,
        float* __restrict__ outp, int MO) {
    int tid = threadIdx.x;
    int base = blockIdx.x * 64;
    int w = tid >> 6, l = tid & 63;
    int lg = l >> 4, lr = l & 15;
    f32x4 acc[4][2];
#pragma unroll
    for (int t = 0; t < 2; t++) {
        float bv = b5[w * 32 + t * 16 + lr];
#pragma unroll
        for (int m = 0; m < 4; m++) acc[m][t] = (f32x4){bv, bv, bv, bv};
    }
#pragma unroll
    for (int s = 0; s < 4; s++) {
        bf16x8 a[4];
#pragma unroll
        for (int m = 0; m < 4; m++) {
            int row = base + m * 16 + lr;
            a[m] = *reinterpret_cast<const bf16x8*>(&meanB[(size_t)row * 128 + (s * 4 + lg) * 8]);
        }
#pragma unroll
        for (int t = 0; t < 2; t++) {
            bf16x8 b = *reinterpret_cast<const bf16x8*>(P2 + ((size_t)(s * 8 + w * 2 + t) * 64 + l) * 8);
#pragma unroll
            for (int m = 0; m < 4; m++)
                acc[m][t] = __builtin_amdgcn_mfma_f32_16x16x32_bf16(a[m], b, acc[m][t], 0, 0, 0);
        }
    }
#pragma unroll
    for (int m = 0; m < 4; m++)
#pragma unroll
        for (int t = 0; t < 2; t++)
#pragma unroll
            for (int rr = 0; rr < 4; rr++) {
                int row = base + m * 16 + lg * 4 + rr;
                if (row < MO) {
                    float val = (cntI[row] > 0) ? acc[m][t][rr] : 0.0f;
                    outp[(size_t)row * 128 + w * 32 + t * 16 + lr] = val;
                }
            }
}

// ---------------------------------------------------------------------------
extern "C" void kernel_launch(void* const* d_in, const int* in_sizes, int n_in,
                              void* d_out, int out_size, void* d_ws, size_t ws_size,
                              hipStream_t stream) {
    const float* feat = (const float*)d_in[0];
    const int*   inv  = (const int*)d_in[1];
    const int*   cur  = (const int*)d_in[2];
    const int*   nxt  = (const int*)d_in[3];
    const float* W_in = (const float*)d_in[6];
    const float* b_in = (const float*)d_in[7];
    const float* W1   = (const float*)d_in[8];
    const float* b1   = (const float*)d_in[9];
    const float* g1   = (const float*)d_in[10];
    const float* be1  = (const float*)d_in[11];
    const float* W2   = (const float*)d_in[12];
    const float* b2   = (const float*)d_in[13];
    const float* g2   = (const float*)d_in[14];
    const float* be2  = (const float*)d_in[15];
    const float* W3   = (const float*)d_in[16];
    const float* b3   = (const float*)d_in[17];
    const float* W4   = (const float*)d_in[18];
    const float* b4   = (const float*)d_in[19];
    const float* W5   = (const float*)d_in[20];
    const float* b5   = (const float*)d_in[21];

    const int N  = in_sizes[0] / 64;
    const int NF = in_sizes[2];
    const int MO = out_size / 128;
    const int MD = MDV;   // n_down (device scalar; fixed problem size)

    float* ws = (float*)d_ws;
    size_t off = 0;
    // ---- zeroed region (stats + counters only) ----
    float* ssum1 = ws + off; off += 64;
    float* ssq1  = ws + off; off += 64;
    float* ssum2 = ws + off; off += 64;
    float* ssq2  = ws + off; off += 64;
    int* cntD    = (int*)(ws + off); off += (size_t)MD;
    int* cursorD = (int*)(ws + off); off += (size_t)MD;
    int* cntI    = (int*)(ws + off); off += (size_t)MO;
    int* cursor  = (int*)(ws + off); off += (size_t)MO;
    off = (off + 3) & ~(size_t)3;   // pad zero region to int4 multiple
    size_t zeroElems = off;
    // ---- non-zeroed ----
    float* dsum = ws + off; off += (size_t)MD * 64;
    float* t1   = ws + off; off += (size_t)MD * 64;
    float* t2   = ws + off; off += (size_t)MD * 64;
    float* bp2  = ws + off; off += 64;
    float* bp3  = ws + off; off += 128;
    int* rowstartD = (int*)(ws + off); off += (size_t)MD + 1;
    int* rowstart  = (int*)(ws + off); off += (size_t)MO + 1;
    int* csrD      = (int*)(ws + off); off += (size_t)N;
    off = (off + 1) & ~(size_t)1;   // 8B align for int2
    int2* csrAB    = (int2*)(ws + off); off += (size_t)NF * 2;
    bf16_t* bws = (bf16_t*)(ws + off);
    size_t boff = 0;
    bf16_t* z1    = bws + boff; boff += (size_t)N * 128;
    bf16_t* z2    = bws + boff; boff += (size_t)MD * 128;
    bf16_t* meanB = bws + boff; boff += (size_t)MO * 128 + 4096;  // +slack for tail OOB reads
    bf16_t* P0    = bws + boff; boff += 8192;
    bf16_t* P1    = bws + boff; boff += 32768;
    bf16_t* P2    = bws + boff; boff += 16384;
    bf16_t* P3    = bws + boff; boff += 8192;
    bf16_t* P4    = bws + boff; boff += 4096;
    bf16_t* P5    = bws + boff; boff += 4096;
    (void)ws_size; (void)n_in;

    // fast parallel zero of the counter/stat region (~400KB, ~100 blocks)
    int n4 = (int)(zeroElems >> 2);
    k_zero<<<(n4 + 255) / 256, 256, 0, stream>>>((int4*)d_ws, n4);

    int gmax = (NF > N ? NF : N);
    k_hist_both<<<(gmax + 255) / 256, 256, 0, stream>>>(inv, cntD, nxt, cntI, N, NF);
    k_scan_both<<<2, 1024, 0, stream>>>(cntD, rowstartD, MD, cntI, rowstart, MO);
    k_fill_both<<<(gmax + 255) / 256, 256, 0, stream>>>(inv, rowstartD, cursorD, csrD,
                                                        nxt, cur, rowstart, cursor,
                                                        csrAB, N, NF);
    k_pack<<<30, 256, 0, stream>>>(W4, W5, W_in, W1, P1, P2, P0, P4);

    // front MLP path: pool -> MFMA layer1 (+stats) -> fold -> MFMA layer2 (+stats) -> fold
    k_downsum<<<(MD + 3) / 4, 256, 0, stream>>>(feat, csrD, rowstartD, cntD, dsum, MD);
    k_mfma_bn<<<(MD + 63) / 64, 256, 0, stream>>>(dsum, P4, b1, t1, ssum1, ssq1, MD);
    k_fold<<<1, 64, 0, stream>>>(ssum1, ssq1, g1, be1, W2, b2, P5, bp2, MD);
    k_mfma_bn<<<(MD + 63) / 64, 256, 0, stream>>>(t1, P5, bp2, t2, ssum2, ssq2, MD);
    k_fold_packed<<<1, 128, 0, stream>>>(ssum2, ssq2, g2, be2, W3, b3, P3, bp3, MD);

    // z2 = leaky(t2 @ Wp3 + bp3) @ W4_bot          [MD x 128], L2-resident
    k_two_gemm<<<(MD + 63) / 64, 256, 0, stream>>>(t2, P3, bp3, P1 + 16384, nullptr, z2, MD);
    // z1 = leaky(feat @ Win + bin) @ W4_top + b4   [N x 128]
    k_two_gemm<<<(N + 63) / 64, 256, 0, stream>>>(feat, P0, b_in, P1, b4, z1, N);

    // per-voxel paired gather-mean of leaky(z1+z2)
    k_gather_mean<<<(MO + 3) / 4, 256, 0, stream>>>(z1, z2, csrAB, rowstart, cntI, meanB, MO);
    // out = meanB @ W5 + b5 (masked where empty)
    k_vox2<<<(MO + 63) / 64, 256, 0, stream>>>(meanB, cntI, P2, b5, (float*)d_out, MO);
}

// Round 14
// 235.787 us; speedup vs baseline: 1.3710x; 1.0144x over previous
//
#include <hip/hip_runtime.h>
#include <hip/hip_bf16.h>

#define NEG_SLOPE 0.1f
#define BN_EPS 1e-5f
#define MDV 25000

typedef __bf16 bf16_t;
typedef bf16_t bf16x8 __attribute__((ext_vector_type(8)));
typedef bf16_t bf16x4 __attribute__((ext_vector_type(4)));
typedef float f32x4 __attribute__((ext_vector_type(4)));

__device__ __forceinline__ float leaky(float x) { return x >= 0.0f ? x : NEG_SLOPE * x; }

// ---------------------------------------------------------------------------
// k_setup: blocks [0,nz) zero the counter region (int4); blocks [nz,nz+30)
// pack W4/W5/W_in (128-wide) and W1 (64-wide) into bf16 MFMA-B fragment order.
__global__ void k_setup(int4* __restrict__ zp, int n4, int nz,
                        const float* __restrict__ W4, const float* __restrict__ W5,
                        const float* __restrict__ Win, const float* __restrict__ W1,
                        bf16_t* __restrict__ P1, bf16_t* __restrict__ P2,
                        bf16_t* __restrict__ P0, bf16_t* __restrict__ P4) {
    if ((int)blockIdx.x < nz) {
        int i = blockIdx.x * 256 + threadIdx.x;
        if (i < n4) zp[i] = make_int4(0, 0, 0, 0);
        return;
    }
    int tid = (blockIdx.x - nz) * 256 + threadIdx.x;
    if (tid < 7168) {   // 128-wide packs
        const float* W; bf16_t* P; int t;
        if (tid < 4096)      { W = W4;  P = P1; t = tid; }
        else if (tid < 6144) { W = W5;  P = P2; t = tid - 4096; }
        else                 { W = Win; P = P0; t = tid - 6144; }
        int l = t & 63;
        int sn = t >> 6;
        int col = (sn & 7) * 16 + (l & 15);
        int k0 = (sn >> 3) * 32 + (l >> 4) * 8;
        bf16_t* dst = P + (size_t)t * 8;
#pragma unroll
        for (int j = 0; j < 8; j++) dst[j] = (bf16_t)W[(size_t)(k0 + j) * 128 + col];
    } else if (tid < 7680) {   // W1 [64x64], 64-wide pack (sn = s*4+n)
        int t = tid - 7168;
        int l = t & 63;
        int sn = t >> 6;   // 0..7
        int col = (sn & 3) * 16 + (l & 15);
        int k0 = (sn >> 2) * 32 + (l >> 4) * 8;
        bf16_t* dst = P4 + (size_t)t * 8;
#pragma unroll
        for (int j = 0; j < 8; j++) dst[j] = (bf16_t)W1[(size_t)(k0 + j) * 64 + col];
    }
}

// ---------------------------------------------------------------------------
// histogram both index arrays in one pass
__global__ void k_hist_both(const int* __restrict__ inv, int* __restrict__ cntD,
                            const int* __restrict__ nxt, int* __restrict__ cntI,
                            int N, int NF) {
    int f = blockIdx.x * 256 + threadIdx.x;
    if (f < N) atomicAdd(&cntD[inv[f]], 1);
    if (f < NF) atomicAdd(&cntI[nxt[f]], 1);
}

// ---------------------------------------------------------------------------
// grain scan: block0 scans cntD[MD]->rowstartD, block1 scans cntI[MO]->rowstart
__global__ __launch_bounds__(1024) void k_scan_both(
        const int* __restrict__ cntD, int* __restrict__ rowstartD, int MD,
        const int* __restrict__ cntI, int* __restrict__ rowstart, int MO) {
    const int* in; int* o1; int M;
    if (blockIdx.x == 0) { in = cntD; o1 = rowstartD; M = MD; }
    else                 { in = cntI; o1 = rowstart;  M = MO; }
    int t = threadIdx.x;
    int T = (M + 1023) >> 10;
    int base = t * T;
    int s1 = 0;
    for (int i = 0; i < T; i++) {
        int idx = base + i;
        s1 += (idx < M) ? in[idx] : 0;
    }
    __shared__ int sa[1024], sb[1024];
    sa[t] = s1;
    __syncthreads();
    int *p = sa, *q = sb;
    for (int off = 1; off < 1024; off <<= 1) {
        int v1 = p[t] + ((t >= off) ? p[t - off] : 0);
        q[t] = v1;
        __syncthreads();
        int* tmp = p; p = q; q = tmp;
    }
    int run1 = p[t] - s1;   // exclusive prefix of this thread's grain
    for (int i = 0; i < T; i++) {
        int idx = base + i;
        if (idx < M) {
            o1[idx] = run1;
            run1 += in[idx];
        }
    }
    if (t == 1023) o1[M] = run1;
}

// ---------------------------------------------------------------------------
// fill both CSR lists; csrD holds f; csrAB holds (cur[f], inv[cur[f]]) packed
__global__ void k_fill_both(const int* __restrict__ inv, const int* __restrict__ rowstartD,
                            int* __restrict__ cursorD, int* __restrict__ csrD,
                            const int* __restrict__ nxt, const int* __restrict__ cur,
                            const int* __restrict__ rowstart, int* __restrict__ cursor,
                            int2* __restrict__ csrAB, int N, int NF) {
    int f = blockIdx.x * 256 + threadIdx.x;
    if (f < N) {
        int v = inv[f];
        int pos = atomicAdd(&cursorD[v], 1);
        csrD[rowstartD[v] + pos] = f;
    }
    if (f < NF) {
        int v = nxt[f];
        int pos = atomicAdd(&cursor[v], 1);
        int c = cur[f];
        csrAB[rowstart[v] + pos] = make_int2(c, inv[c]);
    }
}

// ---------------------------------------------------------------------------
// voxel mean pooling via CSR gather: one wave per voxel, x4 unrolled loads
// (avg cnt = 4: one unrolled iteration covers the typical voxel)
__global__ __launch_bounds__(256) void k_downsum(
        const float* __restrict__ feat, const int* __restrict__ csrD,
        const int* __restrict__ rowstartD, const int* __restrict__ cntD,
        float* __restrict__ dsum, int MD) {
    int w = threadIdx.x >> 6, l = threadIdx.x & 63;
    int vox = blockIdx.x * 4 + w;
    if (vox >= MD) return;
    int cnt = cntD[vox];
    int start = rowstartD[vox];
    float s = 0.f;
    int p = 0;
    for (; p + 4 <= cnt; p += 4) {
        int r0 = csrD[start + p];
        int r1 = csrD[start + p + 1];
        int r2 = csrD[start + p + 2];
        int r3 = csrD[start + p + 3];
        s += feat[(size_t)r0 * 64 + l] + feat[(size_t)r1 * 64 + l]
           + feat[(size_t)r2 * 64 + l] + feat[(size_t)r3 * 64 + l];
    }
    for (; p < cnt; p++) s += feat[(size_t)csrD[start + p] * 64 + l];
    dsum[(size_t)vox * 64 + l] = s / fmaxf((float)cnt, 1.0f);
}

// ---------------------------------------------------------------------------
// k_mfma_bn: out[M,64] f32 = leaky(in[M,64] @ P[64,64] + bias), plus BN stats
// (column sum/sumsq) via register butterfly + 1 atomic pair per (block, col).
// block = 64 rows, 4 waves; wave w owns cols [w*16, w*16+16).
__global__ __launch_bounds__(256) void k_mfma_bn(
        const float* __restrict__ in, const bf16_t* __restrict__ Pb,
        const float* __restrict__ bias, float* __restrict__ out,
        float* __restrict__ ssum, float* __restrict__ ssq, int M) {
    __shared__ bf16_t A[64 * 64];     // 8 KB
    int tid = threadIdx.x;
    int base = blockIdx.x * 64;
    int valid = M - base; if (valid > 64) valid = 64;

    {   // stage A: thread covers row=tid>>2, cols (tid&3)*16..+15; f32->bf16, swizzled
        int r = tid >> 2, q = tid & 3;
        float4 v[4];
        if (r < valid) {
            const float4* src = reinterpret_cast<const float4*>(in + (size_t)(base + r) * 64 + q * 16);
#pragma unroll
            for (int i = 0; i < 4; i++) v[i] = src[i];
        } else {
#pragma unroll
            for (int i = 0; i < 4; i++) v[i] = make_float4(0.f, 0.f, 0.f, 0.f);
        }
        bf16x8 h0, h1;
#pragma unroll
        for (int i = 0; i < 2; i++) {
            h0[i * 4 + 0] = (bf16_t)v[i].x; h0[i * 4 + 1] = (bf16_t)v[i].y;
            h0[i * 4 + 2] = (bf16_t)v[i].z; h0[i * 4 + 3] = (bf16_t)v[i].w;
            h1[i * 4 + 0] = (bf16_t)v[2 + i].x; h1[i * 4 + 1] = (bf16_t)v[2 + i].y;
            h1[i * 4 + 2] = (bf16_t)v[2 + i].z; h1[i * 4 + 3] = (bf16_t)v[2 + i].w;
        }
        int xa = (r & 7) << 3;
        *reinterpret_cast<bf16x8*>(&A[r * 64 + ((q * 16) ^ xa)]) = h0;
        *reinterpret_cast<bf16x8*>(&A[r * 64 + ((q * 16 + 8) ^ xa)]) = h1;
    }
    __syncthreads();

    int w = tid >> 6, l = tid & 63;
    int lg = l >> 4, lr = l & 15;
    int xr = (lr & 7) << 3;
    int col = w * 16 + lr;

    f32x4 acc[4];
    float bv = bias[col];
#pragma unroll
    for (int m = 0; m < 4; m++) acc[m] = (f32x4){bv, bv, bv, bv};
#pragma unroll
    for (int s = 0; s < 2; s++) {
        bf16x8 b = *reinterpret_cast<const bf16x8*>(Pb + ((size_t)((s * 4 + w) * 64 + l)) * 8);
#pragma unroll
        for (int m = 0; m < 4; m++) {
            bf16x8 a = *reinterpret_cast<const bf16x8*>(&A[(m * 16 + lr) * 64 + (((s * 4 + lg) * 8) ^ xr)]);
            acc[m] = __builtin_amdgcn_mfma_f32_16x16x32_bf16(a, b, acc[m], 0, 0, 0);
        }
    }

    float cs = 0.f, cq = 0.f;
#pragma unroll
    for (int m = 0; m < 4; m++) {
#pragma unroll
        for (int rr = 0; rr < 4; rr++) {
            int row = m * 16 + lg * 4 + rr;
            float val = leaky(acc[m][rr]);
            if (row < valid) {
                out[(size_t)(base + row) * 64 + col] = val;
                cs += val;
                cq += val * val;
            }
        }
    }
    cs += __shfl_xor(cs, 16); cs += __shfl_xor(cs, 32);
    cq += __shfl_xor(cq, 16); cq += __shfl_xor(cq, 32);
    if (lg == 0) {
        atomicAdd(&ssum[col], cs);
        atomicAdd(&ssq[col], cq);
    }
}

// ---------------------------------------------------------------------------
// fold BatchNorm into the next layer's weights; emit bf16 MFMA-B packed P
// (64-wide pack: sn=s*4+n) and folded bias.
__global__ void k_fold(const float* __restrict__ ssum, const float* __restrict__ ssq,
                       const float* __restrict__ g, const float* __restrict__ be,
                       const float* __restrict__ W, const float* __restrict__ b,
                       bf16_t* __restrict__ Pp, float* __restrict__ bp, int M) {
    int j = threadIdx.x;   // 0..63 output column
    if (j >= 64) return;
    float fM = (float)M;
    float accb = b[j];
    int n = j >> 4, jr = j & 15;
    for (int k = 0; k < 64; k++) {
        float mu = ssum[k] / fM;
        float var = ssq[k] / fM - mu * mu;
        float rstd = rsqrtf(var + BN_EPS);
        float ak = g[k] * rstd;
        float ck = be[k] - mu * ak;
        float w = W[k * 64 + j];
        accb = fmaf(ck, w, accb);
        int s = k >> 5, l = ((k >> 3) & 3) * 16 + jr, jj = k & 7;
        Pp[((size_t)((s * 4 + n) * 64 + l)) * 8 + jj] = (bf16_t)(ak * w);
    }
    bp[j] = accb;
}

// ---------------------------------------------------------------------------
// fold BN2 into W3 [64x128], writing bf16 MFMA-B packed fragments directly
__global__ void k_fold_packed(const float* __restrict__ ssum, const float* __restrict__ ssq,
                              const float* __restrict__ g, const float* __restrict__ be,
                              const float* __restrict__ W, const float* __restrict__ b,
                              bf16_t* __restrict__ P, float* __restrict__ bp, int M) {
    int j = threadIdx.x;   // 0..127 output column
    if (j >= 128) return;
    float fM = (float)M;
    float accb = b[j];
    int n = j >> 4, jr = j & 15;
    for (int k = 0; k < 64; k++) {
        float mu = ssum[k] / fM;
        float var = ssq[k] / fM - mu * mu;
        float rstd = rsqrtf(var + BN_EPS);
        float ak = g[k] * rstd;
        float ck = be[k] - mu * ak;
        float w = W[k * 128 + j];
        accb = fmaf(ck, w, accb);
        int s = k >> 5, l = ((k >> 3) & 3) * 16 + jr, jj = k & 7;
        P[((size_t)((s * 8 + n) * 64 + l)) * 8 + jj] = (bf16_t)(ak * w);
    }
    bp[j] = accb;
}

// ---------------------------------------------------------------------------
// k_two_gemm: out[M,128] = leaky(in[M,64] @ Pa + ba) @ Pb (+ bb)   (bf16 out)
__global__ __launch_bounds__(256) void k_two_gemm(
        const float* __restrict__ in, const bf16_t* __restrict__ Pa,
        const float* __restrict__ ba, const bf16_t* __restrict__ Pb,
        const float* __restrict__ bb, bf16_t* __restrict__ out, int M) {
    __shared__ bf16_t A[64 * 64];     // 8 KB
    __shared__ bf16_t C[64 * 128];    // 16 KB
    int tid = threadIdx.x;
    int base = blockIdx.x * 64;
    int valid = M - base; if (valid > 64) valid = 64;

    {   // stage A: thread covers row=tid>>2, 16 cols, f32->bf16, swizzled
        int r = tid >> 2, q = tid & 3;
        float4 v[4];
        if (r < valid) {
            const float4* src = reinterpret_cast<const float4*>(in + (size_t)(base + r) * 64 + q * 16);
#pragma unroll
            for (int i = 0; i < 4; i++) v[i] = src[i];
        } else {
#pragma unroll
            for (int i = 0; i < 4; i++) v[i] = make_float4(0.f, 0.f, 0.f, 0.f);
        }
        bf16x8 h0, h1;
#pragma unroll
        for (int i = 0; i < 2; i++) {
            h0[i * 4 + 0] = (bf16_t)v[i].x; h0[i * 4 + 1] = (bf16_t)v[i].y;
            h0[i * 4 + 2] = (bf16_t)v[i].z; h0[i * 4 + 3] = (bf16_t)v[i].w;
            h1[i * 4 + 0] = (bf16_t)v[2 + i].x; h1[i * 4 + 1] = (bf16_t)v[2 + i].y;
            h1[i * 4 + 2] = (bf16_t)v[2 + i].z; h1[i * 4 + 3] = (bf16_t)v[2 + i].w;
        }
        int xa = (r & 7) << 3;
        *reinterpret_cast<bf16x8*>(&A[r * 64 + ((q * 16) ^ xa)]) = h0;
        *reinterpret_cast<bf16x8*>(&A[r * 64 + ((q * 16 + 8) ^ xa)]) = h1;
    }
    __syncthreads();

    int w = tid >> 6, l = tid & 63;
    int lg = l >> 4, lr = l & 15;
    int xr = (lr & 7) << 3;

    // GEMM a: K=64 (2 k-steps), acc init ba, leaky -> C
    f32x4 acc[4][2];
#pragma unroll
    for (int t = 0; t < 2; t++) {
        float bv = ba[w * 32 + t * 16 + lr];
#pragma unroll
        for (int m = 0; m < 4; m++) acc[m][t] = (f32x4){bv, bv, bv, bv};
    }
#pragma unroll
    for (int s = 0; s < 2; s++) {
        bf16x8 a[4];
#pragma unroll
        for (int m = 0; m < 4; m++)
            a[m] = *reinterpret_cast<const bf16x8*>(&A[(m * 16 + lr) * 64 + (((s * 4 + lg) * 8) ^ xr)]);
#pragma unroll
        for (int t = 0; t < 2; t++) {
            bf16x8 b = *reinterpret_cast<const bf16x8*>(Pa + ((size_t)(s * 8 + w * 2 + t) * 64 + l) * 8);
#pragma unroll
            for (int m = 0; m < 4; m++)
                acc[m][t] = __builtin_amdgcn_mfma_f32_16x16x32_bf16(a[m], b, acc[m][t], 0, 0, 0);
        }
    }
#pragma unroll
    for (int m = 0; m < 4; m++)
#pragma unroll
        for (int t = 0; t < 2; t++)
#pragma unroll
            for (int rr = 0; rr < 4; rr++) {
                int row = m * 16 + lg * 4 + rr;
                int col = w * 32 + t * 16 + lr;
                C[row * 128 + (col ^ ((row & 7) << 3))] = (bf16_t)leaky(acc[m][t][rr]);
            }
    __syncthreads();

    // GEMM b: K=128 (4 k-steps), acc init bb (or 0)
    f32x4 acc2[4][2];
#pragma unroll
    for (int t = 0; t < 2; t++) {
        float bv = bb ? bb[w * 32 + t * 16 + lr] : 0.0f;
#pragma unroll
        for (int m = 0; m < 4; m++) acc2[m][t] = (f32x4){bv, bv, bv, bv};
    }
#pragma unroll
    for (int s = 0; s < 4; s++) {
        bf16x8 a[4];
#pragma unroll
        for (int m = 0; m < 4; m++)
            a[m] = *reinterpret_cast<const bf16x8*>(&C[(m * 16 + lr) * 128 + ((s * 32 + lg * 8) ^ xr)]);
#pragma unroll
        for (int t = 0; t < 2; t++) {
            bf16x8 b = *reinterpret_cast<const bf16x8*>(Pb + ((size_t)(s * 8 + w * 2 + t) * 64 + l) * 8);
#pragma unroll
            for (int m = 0; m < 4; m++)
                acc2[m][t] = __builtin_amdgcn_mfma_f32_16x16x32_bf16(a[m], b, acc2[m][t], 0, 0, 0);
        }
    }
    __syncthreads();   // all C reads complete before overwrite

    // overwrite C with acc2 (no activation), then coalesced 16B write-out
#pragma unroll
    for (int m = 0; m < 4; m++)
#pragma unroll
        for (int t = 0; t < 2; t++)
#pragma unroll
            for (int rr = 0; rr < 4; rr++) {
                int row = m * 16 + lg * 4 + rr;
                int col = w * 32 + t * 16 + lr;
                C[row * 128 + (col ^ ((row & 7) << 3))] = (bf16_t)acc2[m][t][rr];
            }
    __syncthreads();
#pragma unroll
    for (int i = 0; i < 4; i++) {
        int u = tid + i * 256;
        int row = u >> 4, seg = u & 15;
        if (row < valid) {
            bf16x8 val = *reinterpret_cast<const bf16x8*>(&C[row * 128 + ((seg * 8) ^ ((row & 7) << 3))]);
            *reinterpret_cast<bf16x8*>(&out[(size_t)(base + row) * 128 + seg * 8]) = val;
        }
    }
}

// ---------------------------------------------------------------------------
// k_gather_mean v3: one wave per output voxel; 4 points per wave instruction
// (quarter q=l>>4 covers point p+q; 16 lanes x bf16x8 = full 256B row), x2
// unroll = 8 points (16 loads) in flight. Butterfly over quarters, quarter 0
// writes the 16B mean chunk.
__global__ __launch_bounds__(256) void k_gather_mean(
        const bf16_t* __restrict__ z1, const bf16_t* __restrict__ z2,
        const int2* __restrict__ csrAB, const int* __restrict__ rowstart,
        const int* __restrict__ cntI, bf16_t* __restrict__ meanB, int MO) {
    int w = threadIdx.x >> 6, l = threadIdx.x & 63;
    int q = l >> 4, sub = l & 15;
    int v = blockIdx.x * 4 + w;
    if (v >= MO) return;
    int cnt = cntI[v];
    int start = rowstart[v];
    float s[8] = {0.f, 0.f, 0.f, 0.f, 0.f, 0.f, 0.f, 0.f};
    int p = 0;
    for (; p + 8 <= cnt; p += 8) {
        int2 e0 = csrAB[start + p + q];
        int2 e1 = csrAB[start + p + 4 + q];
        bf16x8 a0 = *reinterpret_cast<const bf16x8*>(&z1[(size_t)e0.x * 128 + sub * 8]);
        bf16x8 b0 = *reinterpret_cast<const bf16x8*>(&z2[(size_t)e0.y * 128 + sub * 8]);
        bf16x8 a1 = *reinterpret_cast<const bf16x8*>(&z1[(size_t)e1.x * 128 + sub * 8]);
        bf16x8 b1 = *reinterpret_cast<const bf16x8*>(&z2[(size_t)e1.y * 128 + sub * 8]);
#pragma unroll
        for (int j = 0; j < 8; j++) {
            s[j] += leaky((float)a0[j] + (float)b0[j]);
            s[j] += leaky((float)a1[j] + (float)b1[j]);
        }
    }
    for (; p + 4 <= cnt; p += 4) {
        int2 e = csrAB[start + p + q];
        bf16x8 a = *reinterpret_cast<const bf16x8*>(&z1[(size_t)e.x * 128 + sub * 8]);
        bf16x8 b = *reinterpret_cast<const bf16x8*>(&z2[(size_t)e.y * 128 + sub * 8]);
#pragma unroll
        for (int j = 0; j < 8; j++) s[j] += leaky((float)a[j] + (float)b[j]);
    }
    if (q < cnt - p) {   // tail 0..3 points, one per quarter
        int2 e = csrAB[start + p + q];
        bf16x8 a = *reinterpret_cast<const bf16x8*>(&z1[(size_t)e.x * 128 + sub * 8]);
        bf16x8 b = *reinterpret_cast<const bf16x8*>(&z2[(size_t)e.y * 128 + sub * 8]);
#pragma unroll
        for (int j = 0; j < 8; j++) s[j] += leaky((float)a[j] + (float)b[j]);
    }
    float sc = (cnt > 0) ? (1.0f / (float)cnt) : 0.0f;
#pragma unroll
    for (int j = 0; j < 8; j++) {
        s[j] += __shfl_xor(s[j], 16);
        s[j] += __shfl_xor(s[j], 32);
    }
    if (q == 0) {
        bf16x8 mv;
#pragma unroll
        for (int j = 0; j < 8; j++) mv[j] = (bf16_t)(s[j] * sc);
        *reinterpret_cast<bf16x8*>(&meanB[(size_t)v * 128 + sub * 8]) = mv;
    }
}

// ---------------------------------------------------------------------------
// k_vox2: out[MO,128] f32 = meanB[MO,128] @ P2 + b5, masked to 0 where cnt==0
__global__ __launch_bounds__(256) void k_vox2(
        const bf16_t* __restrict__ meanB, const int* __restrict__ cntI,
        const bf16_t* __restrict__ P2, const float* __restrict__ b5,
        float* __restrict__ outp, int MO) {
    int tid = threadIdx.x;
    int base = blockIdx.x * 64;
    int w = tid >> 6, l = tid & 63;
    int lg = l >> 4, lr = l & 15;
    f32x4 acc[4][2];
#pragma unroll
    for (int t = 0; t < 2; t++) {
        float bv = b5[w * 32 + t * 16 + lr];
#pragma unroll
        for (int m = 0; m < 4; m++) acc[m][t] = (f32x4){bv, bv, bv, bv};
    }
#pragma unroll
    for (int s = 0; s < 4; s++) {
        bf16x8 a[4];
#pragma unroll
        for (int m = 0; m < 4; m++) {
            int row = base + m * 16 + lr;
            a[m] = *reinterpret_cast<const bf16x8*>(&meanB[(size_t)row * 128 + (s * 4 + lg) * 8]);
        }
#pragma unroll
        for (int t = 0; t < 2; t++) {
            bf16x8 b = *reinterpret_cast<const bf16x8*>(P2 + ((size_t)(s * 8 + w * 2 + t) * 64 + l) * 8);
#pragma unroll
            for (int m = 0; m < 4; m++)
                acc[m][t] = __builtin_amdgcn_mfma_f32_16x16x32_bf16(a[m], b, acc[m][t], 0, 0, 0);
        }
    }
#pragma unroll
    for (int m = 0; m < 4; m++)
#pragma unroll
        for (int t = 0; t < 2; t++)
#pragma unroll
            for (int rr = 0; rr < 4; rr++) {
                int row = base + m * 16 + lg * 4 + rr;
                if (row < MO) {
                    float val = (cntI[row] > 0) ? acc[m][t][rr] : 0.0f;
                    outp[(size_t)row * 128 + w * 32 + t * 16 + lr] = val;
                }
            }
}

// ---------------------------------------------------------------------------
extern "C" void kernel_launch(void* const* d_in, const int* in_sizes, int n_in,
                              void* d_out, int out_size, void* d_ws, size_t ws_size,
                              hipStream_t stream) {
    const float* feat = (const float*)d_in[0];
    const int*   inv  = (const int*)d_in[1];
    const int*   cur  = (const int*)d_in[2];
    const int*   nxt  = (const int*)d_in[3];
    const float* W_in = (const float*)d_in[6];
    const float* b_in = (const float*)d_in[7];
    const float* W1   = (const float*)d_in[8];
    const float* b1   = (const float*)d_in[9];
    const float* g1   = (const float*)d_in[10];
    const float* be1  = (const float*)d_in[11];
    const float* W2   = (const float*)d_in[12];
    const float* b2   = (const float*)d_in[13];
    const float* g2   = (const float*)d_in[14];
    const float* be2  = (const float*)d_in[15];
    const float* W3   = (const float*)d_in[16];
    const float* b3   = (const float*)d_in[17];
    const float* W4   = (const float*)d_in[18];
    const float* b4   = (const float*)d_in[19];
    const float* W5   = (const float*)d_in[20];
    const float* b5   = (const float*)d_in[21];

    const int N  = in_sizes[0] / 64;
    const int NF = in_sizes[2];
    const int MO = out_size / 128;
    const int MD = MDV;   // n_down (device scalar; fixed problem size)

    float* ws = (float*)d_ws;
    size_t off = 0;
    // ---- zeroed region (stats + counters only) ----
    float* ssum1 = ws + off; off += 64;
    float* ssq1  = ws + off; off += 64;
    float* ssum2 = ws + off; off += 64;
    float* ssq2  = ws + off; off += 64;
    int* cntD    = (int*)(ws + off); off += (size_t)MD;
    int* cursorD = (int*)(ws + off); off += (size_t)MD;
    int* cntI    = (int*)(ws + off); off += (size_t)MO;
    int* cursor  = (int*)(ws + off); off += (size_t)MO;
    off = (off + 3) & ~(size_t)3;   // pad zero region to int4 multiple
    size_t zeroElems = off;
    // ---- non-zeroed ----
    float* dsum = ws + off; off += (size_t)MD * 64;
    float* t1   = ws + off; off += (size_t)MD * 64;
    float* t2   = ws + off; off += (size_t)MD * 64;
    float* bp2  = ws + off; off += 64;
    float* bp3  = ws + off; off += 128;
    int* rowstartD = (int*)(ws + off); off += (size_t)MD + 1;
    int* rowstart  = (int*)(ws + off); off += (size_t)MO + 1;
    int* csrD      = (int*)(ws + off); off += (size_t)N;
    off = (off + 1) & ~(size_t)1;   // 8B align for int2
    int2* csrAB    = (int2*)(ws + off); off += (size_t)NF * 2;
    bf16_t* bws = (bf16_t*)(ws + off);
    size_t boff = 0;
    bf16_t* z1    = bws + boff; boff += (size_t)N * 128;
    bf16_t* z2    = bws + boff; boff += (size_t)MD * 128;
    bf16_t* meanB = bws + boff; boff += (size_t)MO * 128 + 4096;  // +slack for tail OOB reads
    bf16_t* P0    = bws + boff; boff += 8192;
    bf16_t* P1    = bws + boff; boff += 32768;
    bf16_t* P2    = bws + boff; boff += 16384;
    bf16_t* P3    = bws + boff; boff += 8192;
    bf16_t* P4    = bws + boff; boff += 4096;
    bf16_t* P5    = bws + boff; boff += 4096;
    (void)ws_size; (void)n_in;

    // fused setup: zero counter region + pack weights (independent block ranges)
    int n4 = (int)(zeroElems >> 2);
    int nz = (n4 + 255) / 256;
    k_setup<<<nz + 30, 256, 0, stream>>>((int4*)d_ws, n4, nz, W4, W5, W_in, W1, P1, P2, P0, P4);

    int gmax = (NF > N ? NF : N);
    k_hist_both<<<(gmax + 255) / 256, 256, 0, stream>>>(inv, cntD, nxt, cntI, N, NF);
    k_scan_both<<<2, 1024, 0, stream>>>(cntD, rowstartD, MD, cntI, rowstart, MO);
    k_fill_both<<<(gmax + 255) / 256, 256, 0, stream>>>(inv, rowstartD, cursorD, csrD,
                                                        nxt, cur, rowstart, cursor,
                                                        csrAB, N, NF);

    // front MLP path: pool -> MFMA layer1 (+stats) -> fold -> MFMA layer2 (+stats) -> fold
    k_downsum<<<(MD + 3) / 4, 256, 0, stream>>>(feat, csrD, rowstartD, cntD, dsum, MD);
    k_mfma_bn<<<(MD + 63) / 64, 256, 0, stream>>>(dsum, P4, b1, t1, ssum1, ssq1, MD);
    k_fold<<<1, 64, 0, stream>>>(ssum1, ssq1, g1, be1, W2, b2, P5, bp2, MD);
    k_mfma_bn<<<(MD + 63) / 64, 256, 0, stream>>>(t1, P5, bp2, t2, ssum2, ssq2, MD);
    k_fold_packed<<<1, 128, 0, stream>>>(ssum2, ssq2, g2, be2, W3, b3, P3, bp3, MD);

    // z2 = leaky(t2 @ Wp3 + bp3) @ W4_bot          [MD x 128], L2-resident
    k_two_gemm<<<(MD + 63) / 64, 256, 0, stream>>>(t2, P3, bp3, P1 + 16384, nullptr, z2, MD);
    // z1 = leaky(feat @ Win + bin) @ W4_top + b4   [N x 128]
    k_two_gemm<<<(N + 63) / 64, 256, 0, stream>>>(feat, P0, b_in, P1, b4, z1, N);

    // per-voxel quarter-based gather-mean of leaky(z1+z2)
    k_gather_mean<<<(MO + 3) / 4, 256, 0, stream>>>(z1, z2, csrAB, rowstart, cntI, meanB, MO);
    // out = meanB @ W5 + b5 (masked where empty)
    k_vox2<<<(MO + 63) / 64, 256, 0, stream>>>(meanB, cntI, P2, b5, (float*)d_out, MO);
}

// Round 15
// 229.077 us; speedup vs baseline: 1.4111x; 1.0293x over previous
//
#include <hip/hip_runtime.h>
#include <hip/hip_bf16.h>

#define NEG_SLOPE 0.1f
#define BN_EPS 1e-5f
#define MDV 25000

typedef __bf16 bf16_t;
typedef bf16_t bf16x8 __attribute__((ext_vector_type(8)));
typedef bf16_t bf16x4 __attribute__((ext_vector_type(4)));
typedef float f32x4 __attribute__((ext_vector_type(4)));

__device__ __forceinline__ float leaky(float x) { return x >= 0.0f ? x : NEG_SLOPE * x; }

// ---------------------------------------------------------------------------
// k_setup: blocks [0,nz) zero the counter region (int4); blocks [nz,nz+30)
// pack W4/W5/W_in (128-wide) and W1 (64-wide) into bf16 MFMA-B fragment order.
__global__ void k_setup(int4* __restrict__ zp, int n4, int nz,
                        const float* __restrict__ W4, const float* __restrict__ W5,
                        const float* __restrict__ Win, const float* __restrict__ W1,
                        bf16_t* __restrict__ P1, bf16_t* __restrict__ P2,
                        bf16_t* __restrict__ P0, bf16_t* __restrict__ P4) {
    if ((int)blockIdx.x < nz) {
        int i = blockIdx.x * 256 + threadIdx.x;
        if (i < n4) zp[i] = make_int4(0, 0, 0, 0);
        return;
    }
    int tid = (blockIdx.x - nz) * 256 + threadIdx.x;
    if (tid < 7168) {   // 128-wide packs
        const float* W; bf16_t* P; int t;
        if (tid < 4096)      { W = W4;  P = P1; t = tid; }
        else if (tid < 6144) { W = W5;  P = P2; t = tid - 4096; }
        else                 { W = Win; P = P0; t = tid - 6144; }
        int l = t & 63;
        int sn = t >> 6;
        int col = (sn & 7) * 16 + (l & 15);
        int k0 = (sn >> 3) * 32 + (l >> 4) * 8;
        bf16_t* dst = P + (size_t)t * 8;
#pragma unroll
        for (int j = 0; j < 8; j++) dst[j] = (bf16_t)W[(size_t)(k0 + j) * 128 + col];
    } else if (tid < 7680) {   // W1 [64x64], 64-wide pack (sn = s*4+n)
        int t = tid - 7168;
        int l = t & 63;
        int sn = t >> 6;   // 0..7
        int col = (sn & 3) * 16 + (l & 15);
        int k0 = (sn >> 2) * 32 + (l >> 4) * 8;
        bf16_t* dst = P4 + (size_t)t * 8;
#pragma unroll
        for (int j = 0; j < 8; j++) dst[j] = (bf16_t)W1[(size_t)(k0 + j) * 64 + col];
    }
}

// ---------------------------------------------------------------------------
// histogram both index arrays in one pass
__global__ void k_hist_both(const int* __restrict__ inv, int* __restrict__ cntD,
                            const int* __restrict__ nxt, int* __restrict__ cntI,
                            int N, int NF) {
    int f = blockIdx.x * 256 + threadIdx.x;
    if (f < N) atomicAdd(&cntD[inv[f]], 1);
    if (f < NF) atomicAdd(&cntI[nxt[f]], 1);
}

// ---------------------------------------------------------------------------
// grain scan: block0 scans cntD[MD]->rowstartD, block1 scans cntI[MO]->rowstart
__global__ __launch_bounds__(1024) void k_scan_both(
        const int* __restrict__ cntD, int* __restrict__ rowstartD, int MD,
        const int* __restrict__ cntI, int* __restrict__ rowstart, int MO) {
    const int* in; int* o1; int M;
    if (blockIdx.x == 0) { in = cntD; o1 = rowstartD; M = MD; }
    else                 { in = cntI; o1 = rowstart;  M = MO; }
    int t = threadIdx.x;
    int T = (M + 1023) >> 10;
    int base = t * T;
    int s1 = 0;
    for (int i = 0; i < T; i++) {
        int idx = base + i;
        s1 += (idx < M) ? in[idx] : 0;
    }
    __shared__ int sa[1024], sb[1024];
    sa[t] = s1;
    __syncthreads();
    int *p = sa, *q = sb;
    for (int off = 1; off < 1024; off <<= 1) {
        int v1 = p[t] + ((t >= off) ? p[t - off] : 0);
        q[t] = v1;
        __syncthreads();
        int* tmp = p; p = q; q = tmp;
    }
    int run1 = p[t] - s1;   // exclusive prefix of this thread's grain
    for (int i = 0; i < T; i++) {
        int idx = base + i;
        if (idx < M) {
            o1[idx] = run1;
            run1 += in[idx];
        }
    }
    if (t == 1023) o1[M] = run1;
}

// ---------------------------------------------------------------------------
// fill both CSR lists; csrD holds f; csrAB holds (cur[f], inv[cur[f]]) packed
__global__ void k_fill_both(const int* __restrict__ inv, const int* __restrict__ rowstartD,
                            int* __restrict__ cursorD, int* __restrict__ csrD,
                            const int* __restrict__ nxt, const int* __restrict__ cur,
                            const int* __restrict__ rowstart, int* __restrict__ cursor,
                            int2* __restrict__ csrAB, int N, int NF) {
    int f = blockIdx.x * 256 + threadIdx.x;
    if (f < N) {
        int v = inv[f];
        int pos = atomicAdd(&cursorD[v], 1);
        csrD[rowstartD[v] + pos] = f;
    }
    if (f < NF) {
        int v = nxt[f];
        int pos = atomicAdd(&cursor[v], 1);
        int c = cur[f];
        csrAB[rowstart[v] + pos] = make_int2(c, inv[c]);
    }
}

// ---------------------------------------------------------------------------
// k_downsum v2: one wave per voxel; quarter q covers point p+q, 16 lanes x
// float4 per 256B row, x2 unroll (8 row-loads in flight). Butterfly over
// quarters; quarter 0 writes the float4 mean chunk.
__global__ __launch_bounds__(256) void k_downsum(
        const float* __restrict__ feat, const int* __restrict__ csrD,
        const int* __restrict__ rowstartD, const int* __restrict__ cntD,
        float* __restrict__ dsum, int MD) {
    int w = threadIdx.x >> 6, l = threadIdx.x & 63;
    int q = l >> 4, sub = l & 15;
    int vox = blockIdx.x * 4 + w;
    if (vox >= MD) return;
    int cnt = cntD[vox];
    int start = rowstartD[vox];
    float4 s = make_float4(0.f, 0.f, 0.f, 0.f);
    int p = 0;
    for (; p + 8 <= cnt; p += 8) {
        int r0 = csrD[start + p + q];
        int r1 = csrD[start + p + 4 + q];
        float4 v0 = *reinterpret_cast<const float4*>(&feat[(size_t)r0 * 64 + sub * 4]);
        float4 v1 = *reinterpret_cast<const float4*>(&feat[(size_t)r1 * 64 + sub * 4]);
        s.x += v0.x + v1.x; s.y += v0.y + v1.y;
        s.z += v0.z + v1.z; s.w += v0.w + v1.w;
    }
    for (; p + 4 <= cnt; p += 4) {
        int r0 = csrD[start + p + q];
        float4 v0 = *reinterpret_cast<const float4*>(&feat[(size_t)r0 * 64 + sub * 4]);
        s.x += v0.x; s.y += v0.y; s.z += v0.z; s.w += v0.w;
    }
    if (q < cnt - p) {   // tail 0..3 points, one per quarter
        int r0 = csrD[start + p + q];
        float4 v0 = *reinterpret_cast<const float4*>(&feat[(size_t)r0 * 64 + sub * 4]);
        s.x += v0.x; s.y += v0.y; s.z += v0.z; s.w += v0.w;
    }
    s.x += __shfl_xor(s.x, 16); s.x += __shfl_xor(s.x, 32);
    s.y += __shfl_xor(s.y, 16); s.y += __shfl_xor(s.y, 32);
    s.z += __shfl_xor(s.z, 16); s.z += __shfl_xor(s.z, 32);
    s.w += __shfl_xor(s.w, 16); s.w += __shfl_xor(s.w, 32);
    if (q == 0) {
        float sc = (cnt > 0) ? (1.0f / (float)cnt) : 0.0f;
        float4 mv = make_float4(s.x * sc, s.y * sc, s.z * sc, s.w * sc);
        *reinterpret_cast<float4*>(&dsum[(size_t)vox * 64 + sub * 4]) = mv;
    }
}

// ---------------------------------------------------------------------------
// k_mfma_bn: out[M,64] f32 = leaky(in[M,64] @ P[64,64] + bias), plus BN stats
// (column sum/sumsq) via register butterfly + 1 atomic pair per (block, col).
__global__ __launch_bounds__(256) void k_mfma_bn(
        const float* __restrict__ in, const bf16_t* __restrict__ Pb,
        const float* __restrict__ bias, float* __restrict__ out,
        float* __restrict__ ssum, float* __restrict__ ssq, int M) {
    __shared__ bf16_t A[64 * 64];     // 8 KB
    int tid = threadIdx.x;
    int base = blockIdx.x * 64;
    int valid = M - base; if (valid > 64) valid = 64;

    {   // stage A: thread covers row=tid>>2, cols (tid&3)*16..+15; f32->bf16, swizzled
        int r = tid >> 2, q = tid & 3;
        float4 v[4];
        if (r < valid) {
            const float4* src = reinterpret_cast<const float4*>(in + (size_t)(base + r) * 64 + q * 16);
#pragma unroll
            for (int i = 0; i < 4; i++) v[i] = src[i];
        } else {
#pragma unroll
            for (int i = 0; i < 4; i++) v[i] = make_float4(0.f, 0.f, 0.f, 0.f);
        }
        bf16x8 h0, h1;
#pragma unroll
        for (int i = 0; i < 2; i++) {
            h0[i * 4 + 0] = (bf16_t)v[i].x; h0[i * 4 + 1] = (bf16_t)v[i].y;
            h0[i * 4 + 2] = (bf16_t)v[i].z; h0[i * 4 + 3] = (bf16_t)v[i].w;
            h1[i * 4 + 0] = (bf16_t)v[2 + i].x; h1[i * 4 + 1] = (bf16_t)v[2 + i].y;
            h1[i * 4 + 2] = (bf16_t)v[2 + i].z; h1[i * 4 + 3] = (bf16_t)v[2 + i].w;
        }
        int xa = (r & 7) << 3;
        *reinterpret_cast<bf16x8*>(&A[r * 64 + ((q * 16) ^ xa)]) = h0;
        *reinterpret_cast<bf16x8*>(&A[r * 64 + ((q * 16 + 8) ^ xa)]) = h1;
    }
    __syncthreads();

    int w = tid >> 6, l = tid & 63;
    int lg = l >> 4, lr = l & 15;
    int xr = (lr & 7) << 3;
    int col = w * 16 + lr;

    f32x4 acc[4];
    float bv = bias[col];
#pragma unroll
    for (int m = 0; m < 4; m++) acc[m] = (f32x4){bv, bv, bv, bv};
#pragma unroll
    for (int s = 0; s < 2; s++) {
        bf16x8 b = *reinterpret_cast<const bf16x8*>(Pb + ((size_t)((s * 4 + w) * 64 + l)) * 8);
#pragma unroll
        for (int m = 0; m < 4; m++) {
            bf16x8 a = *reinterpret_cast<const bf16x8*>(&A[(m * 16 + lr) * 64 + (((s * 4 + lg) * 8) ^ xr)]);
            acc[m] = __builtin_amdgcn_mfma_f32_16x16x32_bf16(a, b, acc[m], 0, 0, 0);
        }
    }

    float cs = 0.f, cq = 0.f;
#pragma unroll
    for (int m = 0; m < 4; m++) {
#pragma unroll
        for (int rr = 0; rr < 4; rr++) {
            int row = m * 16 + lg * 4 + rr;
            float val = leaky(acc[m][rr]);
            if (row < valid) {
                out[(size_t)(base + row) * 64 + col] = val;
                cs += val;
                cq += val * val;
            }
        }
    }
    cs += __shfl_xor(cs, 16); cs += __shfl_xor(cs, 32);
    cq += __shfl_xor(cq, 16); cq += __shfl_xor(cq, 32);
    if (lg == 0) {
        atomicAdd(&ssum[col], cs);
        atomicAdd(&ssq[col], cq);
    }
}

// ---------------------------------------------------------------------------
// fold BatchNorm into the next layer's weights; emit bf16 MFMA-B packed P
// (64-wide pack: sn=s*4+n) and folded bias.
__global__ void k_fold(const float* __restrict__ ssum, const float* __restrict__ ssq,
                       const float* __restrict__ g, const float* __restrict__ be,
                       const float* __restrict__ W, const float* __restrict__ b,
                       bf16_t* __restrict__ Pp, float* __restrict__ bp, int M) {
    int j = threadIdx.x;   // 0..63 output column
    if (j >= 64) return;
    float fM = (float)M;
    float accb = b[j];
    int n = j >> 4, jr = j & 15;
    for (int k = 0; k < 64; k++) {
        float mu = ssum[k] / fM;
        float var = ssq[k] / fM - mu * mu;
        float rstd = rsqrtf(var + BN_EPS);
        float ak = g[k] * rstd;
        float ck = be[k] - mu * ak;
        float w = W[k * 64 + j];
        accb = fmaf(ck, w, accb);
        int s = k >> 5, l = ((k >> 3) & 3) * 16 + jr, jj = k & 7;
        Pp[((size_t)((s * 4 + n) * 64 + l)) * 8 + jj] = (bf16_t)(ak * w);
    }
    bp[j] = accb;
}

// ---------------------------------------------------------------------------
// fold BN2 into W3 [64x128], writing bf16 MFMA-B packed fragments directly
__global__ void k_fold_packed(const float* __restrict__ ssum, const float* __restrict__ ssq,
                              const float* __restrict__ g, const float* __restrict__ be,
                              const float* __restrict__ W, const float* __restrict__ b,
                              bf16_t* __restrict__ P, float* __restrict__ bp, int M) {
    int j = threadIdx.x;   // 0..127 output column
    if (j >= 128) return;
    float fM = (float)M;
    float accb = b[j];
    int n = j >> 4, jr = j & 15;
    for (int k = 0; k < 64; k++) {
        float mu = ssum[k] / fM;
        float var = ssq[k] / fM - mu * mu;
        float rstd = rsqrtf(var + BN_EPS);
        float ak = g[k] * rstd;
        float ck = be[k] - mu * ak;
        float w = W[k * 128 + j];
        accb = fmaf(ck, w, accb);
        int s = k >> 5, l = ((k >> 3) & 3) * 16 + jr, jj = k & 7;
        P[((size_t)((s * 8 + n) * 64 + l)) * 8 + jj] = (bf16_t)(ak * w);
    }
    bp[j] = accb;
}

// ---------------------------------------------------------------------------
// two_gemm tile body: out[64,128] tile = leaky(in@Pa + ba) @ Pb (+ bb)
__device__ __forceinline__ void two_gemm_tile(
        const float* __restrict__ in, const bf16_t* __restrict__ Pa,
        const float* __restrict__ ba, const bf16_t* __restrict__ Pb,
        const float* __restrict__ bb, bf16_t* __restrict__ out,
        int M, int base, bf16_t* A, bf16_t* C) {
    int tid = threadIdx.x;
    int valid = M - base; if (valid > 64) valid = 64;

    {   // stage A: thread covers row=tid>>2, 16 cols, f32->bf16, swizzled
        int r = tid >> 2, q = tid & 3;
        float4 v[4];
        if (r < valid) {
            const float4* src = reinterpret_cast<const float4*>(in + (size_t)(base + r) * 64 + q * 16);
#pragma unroll
            for (int i = 0; i < 4; i++) v[i] = src[i];
        } else {
#pragma unroll
            for (int i = 0; i < 4; i++) v[i] = make_float4(0.f, 0.f, 0.f, 0.f);
        }
        bf16x8 h0, h1;
#pragma unroll
        for (int i = 0; i < 2; i++) {
            h0[i * 4 + 0] = (bf16_t)v[i].x; h0[i * 4 + 1] = (bf16_t)v[i].y;
            h0[i * 4 + 2] = (bf16_t)v[i].z; h0[i * 4 + 3] = (bf16_t)v[i].w;
            h1[i * 4 + 0] = (bf16_t)v[2 + i].x; h1[i * 4 + 1] = (bf16_t)v[2 + i].y;
            h1[i * 4 + 2] = (bf16_t)v[2 + i].z; h1[i * 4 + 3] = (bf16_t)v[2 + i].w;
        }
        int xa = (r & 7) << 3;
        *reinterpret_cast<bf16x8*>(&A[r * 64 + ((q * 16) ^ xa)]) = h0;
        *reinterpret_cast<bf16x8*>(&A[r * 64 + ((q * 16 + 8) ^ xa)]) = h1;
    }
    __syncthreads();

    int w = tid >> 6, l = tid & 63;
    int lg = l >> 4, lr = l & 15;
    int xr = (lr & 7) << 3;

    // GEMM a: K=64 (2 k-steps), acc init ba, leaky -> C
    f32x4 acc[4][2];
#pragma unroll
    for (int t = 0; t < 2; t++) {
        float bv = ba[w * 32 + t * 16 + lr];
#pragma unroll
        for (int m = 0; m < 4; m++) acc[m][t] = (f32x4){bv, bv, bv, bv};
    }
#pragma unroll
    for (int s = 0; s < 2; s++) {
        bf16x8 a[4];
#pragma unroll
        for (int m = 0; m < 4; m++)
            a[m] = *reinterpret_cast<const bf16x8*>(&A[(m * 16 + lr) * 64 + (((s * 4 + lg) * 8) ^ xr)]);
#pragma unroll
        for (int t = 0; t < 2; t++) {
            bf16x8 b = *reinterpret_cast<const bf16x8*>(Pa + ((size_t)(s * 8 + w * 2 + t) * 64 + l) * 8);
#pragma unroll
            for (int m = 0; m < 4; m++)
                acc[m][t] = __builtin_amdgcn_mfma_f32_16x16x32_bf16(a[m], b, acc[m][t], 0, 0, 0);
        }
    }
#pragma unroll
    for (int m = 0; m < 4; m++)
#pragma unroll
        for (int t = 0; t < 2; t++)
#pragma unroll
            for (int rr = 0; rr < 4; rr++) {
                int row = m * 16 + lg * 4 + rr;
                int col = w * 32 + t * 16 + lr;
                C[row * 128 + (col ^ ((row & 7) << 3))] = (bf16_t)leaky(acc[m][t][rr]);
            }
    __syncthreads();

    // GEMM b: K=128 (4 k-steps), acc init bb (or 0)
    f32x4 acc2[4][2];
#pragma unroll
    for (int t = 0; t < 2; t++) {
        float bv = bb ? bb[w * 32 + t * 16 + lr] : 0.0f;
#pragma unroll
        for (int m = 0; m < 4; m++) acc2[m][t] = (f32x4){bv, bv, bv, bv};
    }
#pragma unroll
    for (int s = 0; s < 4; s++) {
        bf16x8 a[4];
#pragma unroll
        for (int m = 0; m < 4; m++)
            a[m] = *reinterpret_cast<const bf16x8*>(&C[(m * 16 + lr) * 128 + ((s * 32 + lg * 8) ^ xr)]);
#pragma unroll
        for (int t = 0; t < 2; t++) {
            bf16x8 b = *reinterpret_cast<const bf16x8*>(Pb + ((size_t)(s * 8 + w * 2 + t) * 64 + l) * 8);
#pragma unroll
            for (int m = 0; m < 4; m++)
                acc2[m][t] = __builtin_amdgcn_mfma_f32_16x16x32_bf16(a[m], b, acc2[m][t], 0, 0, 0);
        }
    }
    __syncthreads();   // all C reads complete before overwrite

    // overwrite C with acc2, then coalesced 16B write-out
#pragma unroll
    for (int m = 0; m < 4; m++)
#pragma unroll
        for (int t = 0; t < 2; t++)
#pragma unroll
            for (int rr = 0; rr < 4; rr++) {
                int row = m * 16 + lg * 4 + rr;
                int col = w * 32 + t * 16 + lr;
                C[row * 128 + (col ^ ((row & 7) << 3))] = (bf16_t)acc2[m][t][rr];
            }
    __syncthreads();
#pragma unroll
    for (int i = 0; i < 4; i++) {
        int u = tid + i * 256;
        int row = u >> 4, seg = u & 15;
        if (row < valid) {
            bf16x8 val = *reinterpret_cast<const bf16x8*>(&C[row * 128 + ((seg * 8) ^ ((row & 7) << 3))]);
            *reinterpret_cast<bf16x8*>(&out[(size_t)(base + row) * 128 + seg * 8]) = val;
        }
    }
}

// merged launch: blocks [0,nt1) compute z2 tiles; [nt1, nt1+nt2) compute z1 tiles
__global__ __launch_bounds__(256) void k_two_gemm2(
        const float* __restrict__ in1, const bf16_t* __restrict__ Pa1,
        const float* __restrict__ ba1, const bf16_t* __restrict__ Pb1,
        bf16_t* __restrict__ out1, int M1, int nt1,
        const float* __restrict__ in2, const bf16_t* __restrict__ Pa2,
        const float* __restrict__ ba2, const bf16_t* __restrict__ Pb2,
        const float* __restrict__ bb2, bf16_t* __restrict__ out2, int M2) {
    __shared__ bf16_t A[64 * 64];     // 8 KB
    __shared__ bf16_t C[64 * 128];    // 16 KB
    int b = blockIdx.x;
    if (b < nt1)
        two_gemm_tile(in1, Pa1, ba1, Pb1, nullptr, out1, M1, b * 64, A, C);
    else
        two_gemm_tile(in2, Pa2, ba2, Pb2, bb2, out2, M2, (b - nt1) * 64, A, C);
}

// ---------------------------------------------------------------------------
// k_gather_mean v3: one wave per output voxel; 4 points per wave instruction
// (quarter q covers point p+q; 16 lanes x bf16x8 = full 256B row), 16/8/4-pt
// unroll tiers. Butterfly over quarters; quarter 0 writes the 16B mean chunk.
__global__ __launch_bounds__(256) void k_gather_mean(
        const bf16_t* __restrict__ z1, const bf16_t* __restrict__ z2,
        const int2* __restrict__ csrAB, const int* __restrict__ rowstart,
        const int* __restrict__ cntI, bf16_t* __restrict__ meanB, int MO) {
    int w = threadIdx.x >> 6, l = threadIdx.x & 63;
    int q = l >> 4, sub = l & 15;
    int v = blockIdx.x * 4 + w;
    if (v >= MO) return;
    int cnt = cntI[v];
    int start = rowstart[v];
    float s[8] = {0.f, 0.f, 0.f, 0.f, 0.f, 0.f, 0.f, 0.f};
    int p = 0;
    for (; p + 16 <= cnt; p += 16) {
        int2 e0 = csrAB[start + p + q];
        int2 e1 = csrAB[start + p + 4 + q];
        int2 e2 = csrAB[start + p + 8 + q];
        int2 e3 = csrAB[start + p + 12 + q];
        bf16x8 a0 = *reinterpret_cast<const bf16x8*>(&z1[(size_t)e0.x * 128 + sub * 8]);
        bf16x8 b0 = *reinterpret_cast<const bf16x8*>(&z2[(size_t)e0.y * 128 + sub * 8]);
        bf16x8 a1 = *reinterpret_cast<const bf16x8*>(&z1[(size_t)e1.x * 128 + sub * 8]);
        bf16x8 b1 = *reinterpret_cast<const bf16x8*>(&z2[(size_t)e1.y * 128 + sub * 8]);
        bf16x8 a2 = *reinterpret_cast<const bf16x8*>(&z1[(size_t)e2.x * 128 + sub * 8]);
        bf16x8 b2 = *reinterpret_cast<const bf16x8*>(&z2[(size_t)e2.y * 128 + sub * 8]);
        bf16x8 a3 = *reinterpret_cast<const bf16x8*>(&z1[(size_t)e3.x * 128 + sub * 8]);
        bf16x8 b3 = *reinterpret_cast<const bf16x8*>(&z2[(size_t)e3.y * 128 + sub * 8]);
#pragma unroll
        for (int j = 0; j < 8; j++) {
            s[j] += leaky((float)a0[j] + (float)b0[j]);
            s[j] += leaky((float)a1[j] + (float)b1[j]);
            s[j] += leaky((float)a2[j] + (float)b2[j]);
            s[j] += leaky((float)a3[j] + (float)b3[j]);
        }
    }
    for (; p + 8 <= cnt; p += 8) {
        int2 e0 = csrAB[start + p + q];
        int2 e1 = csrAB[start + p + 4 + q];
        bf16x8 a0 = *reinterpret_cast<const bf16x8*>(&z1[(size_t)e0.x * 128 + sub * 8]);
        bf16x8 b0 = *reinterpret_cast<const bf16x8*>(&z2[(size_t)e0.y * 128 + sub * 8]);
        bf16x8 a1 = *reinterpret_cast<const bf16x8*>(&z1[(size_t)e1.x * 128 + sub * 8]);
        bf16x8 b1 = *reinterpret_cast<const bf16x8*>(&z2[(size_t)e1.y * 128 + sub * 8]);
#pragma unroll
        for (int j = 0; j < 8; j++) {
            s[j] += leaky((float)a0[j] + (float)b0[j]);
            s[j] += leaky((float)a1[j] + (float)b1[j]);
        }
    }
    for (; p + 4 <= cnt; p += 4) {
        int2 e = csrAB[start + p + q];
        bf16x8 a = *reinterpret_cast<const bf16x8*>(&z1[(size_t)e.x * 128 + sub * 8]);
        bf16x8 b = *reinterpret_cast<const bf16x8*>(&z2[(size_t)e.y * 128 + sub * 8]);
#pragma unroll
        for (int j = 0; j < 8; j++) s[j] += leaky((float)a[j] + (float)b[j]);
    }
    if (q < cnt - p) {   // tail 0..3 points, one per quarter
        int2 e = csrAB[start + p + q];
        bf16x8 a = *reinterpret_cast<const bf16x8*>(&z1[(size_t)e.x * 128 + sub * 8]);
        bf16x8 b = *reinterpret_cast<const bf16x8*>(&z2[(size_t)e.y * 128 + sub * 8]);
#pragma unroll
        for (int j = 0; j < 8; j++) s[j] += leaky((float)a[j] + (float)b[j]);
    }
    float sc = (cnt > 0) ? (1.0f / (float)cnt) : 0.0f;
#pragma unroll
    for (int j = 0; j < 8; j++) {
        s[j] += __shfl_xor(s[j], 16);
        s[j] += __shfl_xor(s[j], 32);
    }
    if (q == 0) {
        bf16x8 mv;
#pragma unroll
        for (int j = 0; j < 8; j++) mv[j] = (bf16_t)(s[j] * sc);
        *reinterpret_cast<bf16x8*>(&meanB[(size_t)v * 128 + sub * 8]) = mv;
    }
}

// ---------------------------------------------------------------------------
// k_vox2: out[MO,128] f32 = meanB[MO,128] @ P2 + b5, masked to 0 where cnt==0
__global__ __launch_bounds__(256) void k_vox2(
        const bf16_t* __restrict__ meanB, const int* __restrict__ cntI,
        const bf16_t* __restrict__ P2, const float* __restrict__ b5,
        float* __restrict__ outp, int MO) {
    int tid = threadIdx.x;
    int base = blockIdx.x * 64;
    int w = tid >> 6, l = tid & 63;
    int lg = l >> 4, lr = l & 15;
    f32x4 acc[4][2];
#pragma unroll
    for (int t = 0; t < 2; t++) {
        float bv = b5[w * 32 + t * 16 + lr];
#pragma unroll
        for (int m = 0; m < 4; m++) acc[m][t] = (f32x4){bv, bv, bv, bv};
    }
#pragma unroll
    for (int s = 0; s < 4; s++) {
        bf16x8 a[4];
#pragma unroll
        for (int m = 0; m < 4; m++) {
            int row = base + m * 16 + lr;
            a[m] = *reinterpret_cast<const bf16x8*>(&meanB[(size_t)row * 128 + (s * 4 + lg) * 8]);
        }
#pragma unroll
        for (int t = 0; t < 2; t++) {
            bf16x8 b = *reinterpret_cast<const bf16x8*>(P2 + ((size_t)(s * 8 + w * 2 + t) * 64 + l) * 8);
#pragma unroll
            for (int m = 0; m < 4; m++)
                acc[m][t] = __builtin_amdgcn_mfma_f32_16x16x32_bf16(a[m], b, acc[m][t], 0, 0, 0);
        }
    }
#pragma unroll
    for (int m = 0; m < 4; m++)
#pragma unroll
        for (int t = 0; t < 2; t++)
#pragma unroll
            for (int rr = 0; rr < 4; rr++) {
                int row = base + m * 16 + lg * 4 + rr;
                if (row < MO) {
                    float val = (cntI[row] > 0) ? acc[m][t][rr] : 0.0f;
                    outp[(size_t)row * 128 + w * 32 + t * 16 + lr] = val;
                }
            }
}

// ---------------------------------------------------------------------------
extern "C" void kernel_launch(void* const* d_in, const int* in_sizes, int n_in,
                              void* d_out, int out_size, void* d_ws, size_t ws_size,
                              hipStream_t stream) {
    const float* feat = (const float*)d_in[0];
    const int*   inv  = (const int*)d_in[1];
    const int*   cur  = (const int*)d_in[2];
    const int*   nxt  = (const int*)d_in[3];
    const float* W_in = (const float*)d_in[6];
    const float* b_in = (const float*)d_in[7];
    const float* W1   = (const float*)d_in[8];
    const float* b1   = (const float*)d_in[9];
    const float* g1   = (const float*)d_in[10];
    const float* be1  = (const float*)d_in[11];
    const float* W2   = (const float*)d_in[12];
    const float* b2   = (const float*)d_in[13];
    const float* g2   = (const float*)d_in[14];
    const float* be2  = (const float*)d_in[15];
    const float* W3   = (const float*)d_in[16];
    const float* b3   = (const float*)d_in[17];
    const float* W4   = (const float*)d_in[18];
    const float* b4   = (const float*)d_in[19];
    const float* W5   = (const float*)d_in[20];
    const float* b5   = (const float*)d_in[21];

    const int N  = in_sizes[0] / 64;
    const int NF = in_sizes[2];
    const int MO = out_size / 128;
    const int MD = MDV;   // n_down (device scalar; fixed problem size)

    float* ws = (float*)d_ws;
    size_t off = 0;
    // ---- zeroed region (stats + counters only) ----
    float* ssum1 = ws + off; off += 64;
    float* ssq1  = ws + off; off += 64;
    float* ssum2 = ws + off; off += 64;
    float* ssq2  = ws + off; off += 64;
    int* cntD    = (int*)(ws + off); off += (size_t)MD;
    int* cursorD = (int*)(ws + off); off += (size_t)MD;
    int* cntI    = (int*)(ws + off); off += (size_t)MO;
    int* cursor  = (int*)(ws + off); off += (size_t)MO;
    off = (off + 3) & ~(size_t)3;   // pad zero region to int4 multiple
    size_t zeroElems = off;
    // ---- non-zeroed ----
    float* dsum = ws + off; off += (size_t)MD * 64;
    float* t1   = ws + off; off += (size_t)MD * 64;
    float* t2   = ws + off; off += (size_t)MD * 64;
    float* bp2  = ws + off; off += 64;
    float* bp3  = ws + off; off += 128;
    int* rowstartD = (int*)(ws + off); off += (size_t)MD + 1;
    int* rowstart  = (int*)(ws + off); off += (size_t)MO + 1;
    int* csrD      = (int*)(ws + off); off += (size_t)N;
    off = (off + 1) & ~(size_t)1;   // 8B align for int2
    int2* csrAB    = (int2*)(ws + off); off += (size_t)NF * 2;
    bf16_t* bws = (bf16_t*)(ws + off);
    size_t boff = 0;
    bf16_t* z1    = bws + boff; boff += (size_t)N * 128;
    bf16_t* z2    = bws + boff; boff += (size_t)MD * 128;
    bf16_t* meanB = bws + boff; boff += (size_t)MO * 128 + 4096;  // +slack for tail OOB reads
    bf16_t* P0    = bws + boff; boff += 8192;
    bf16_t* P1    = bws + boff; boff += 32768;
    bf16_t* P2    = bws + boff; boff += 16384;
    bf16_t* P3    = bws + boff; boff += 8192;
    bf16_t* P4    = bws + boff; boff += 4096;
    bf16_t* P5    = bws + boff; boff += 4096;
    (void)ws_size; (void)n_in;

    // fused setup: zero counter region + pack weights (independent block ranges)
    int n4 = (int)(zeroElems >> 2);
    int nz = (n4 + 255) / 256;
    k_setup<<<nz + 30, 256, 0, stream>>>((int4*)d_ws, n4, nz, W4, W5, W_in, W1, P1, P2, P0, P4);

    int gmax = (NF > N ? NF : N);
    k_hist_both<<<(gmax + 255) / 256, 256, 0, stream>>>(inv, cntD, nxt, cntI, N, NF);
    k_scan_both<<<2, 1024, 0, stream>>>(cntD, rowstartD, MD, cntI, rowstart, MO);
    k_fill_both<<<(gmax + 255) / 256, 256, 0, stream>>>(inv, rowstartD, cursorD, csrD,
                                                        nxt, cur, rowstart, cursor,
                                                        csrAB, N, NF);

    // front MLP path: pool -> MFMA layer1 (+stats) -> fold -> MFMA layer2 (+stats) -> fold
    k_downsum<<<(MD + 3) / 4, 256, 0, stream>>>(feat, csrD, rowstartD, cntD, dsum, MD);
    k_mfma_bn<<<(MD + 63) / 64, 256, 0, stream>>>(dsum, P4, b1, t1, ssum1, ssq1, MD);
    k_fold<<<1, 64, 0, stream>>>(ssum1, ssq1, g1, be1, W2, b2, P5, bp2, MD);
    k_mfma_bn<<<(MD + 63) / 64, 256, 0, stream>>>(t1, P5, bp2, t2, ssum2, ssq2, MD);
    k_fold_packed<<<1, 128, 0, stream>>>(ssum2, ssq2, g2, be2, W3, b3, P3, bp3, MD);

    // merged: z2 = leaky(t2@Wp3+bp3)@W4_bot ; z1 = leaky(feat@Win+bin)@W4_top + b4
    int nt1 = (MD + 63) / 64;
    int nt2 = (N + 63) / 64;
    k_two_gemm2<<<nt1 + nt2, 256, 0, stream>>>(t2, P3, bp3, P1 + 16384, z2, MD, nt1,
                                               feat, P0, b_in, P1, b4, z1, N);

    // per-voxel quarter-based gather-mean of leaky(z1+z2)
    k_gather_mean<<<(MO + 3) / 4, 256, 0, stream>>>(z1, z2, csrAB, rowstart, cntI, meanB, MO);
    // out = meanB @ W5 + b5 (masked where empty)
    k_vox2<<<(MO + 63) / 64, 256, 0, stream>>>(meanB, cntI, P2, b5, (float*)d_out, MO);
}